// Round 6
// baseline (358.808 us; speedup 1.0000x reference)
//
#include <hip/hip_runtime.h>

// ---------------------------------------------------------------------------
// GAT encoder, 2 layers, MI355X — round 14.
// Dtype-adaptive (probe: f32-vs-bf16 floats, i64-vs-i32 indices).
// bf16 internal, f32 accumulation, direct-sum softmax (logits bounded).
// Ledger of measured lessons:
//  r7  : interleaving both h1 planes doubles FETCH — keep 2 per-plane node1
//        dispatches (hard footprint separation).
//  r9  : node1 8 edges/wave 16-granule = 59.3us/pass. Structure floor:
//        r9/r11/r13 all pin 59-61us @ ~3.15 TB/s L2-miss service.
//  r10 : 32-ch slice passes regress (replicated streams). gemm1_pass2 55us
//        was the PASS2 TAIL (Occ 20%), not gemm.
//  r11 : packed gemm operands fix scattered fragment loads; node1 packed
//        epilogue costs +3us/pass (keep row-major hmidb).
//  r12 : 32-edge granule: VGPR 52, occupancy 37%, node1 74us. REVERTED.
//  r13 : pass2-first + wave-privatized counting sort: 354.5us BEST.
// r14: (a) gemm2 LDS-staged A (fixes scattered 64-line frag loads, the r10
// disease); (b) gemm1 XCD-grouped block map (same row-block's 4 heads on one
// XCD -> A fetched once per XCD); (c) nontemporal csr stream loads.
// 7 dispatches: probe, prep+bucket, pass2+gemm1, node1 x2, gemm2, node2.
// ---------------------------------------------------------------------------

typedef __attribute__((ext_vector_type(8))) short short8;
typedef __attribute__((ext_vector_type(4))) float floatx4;
typedef __attribute__((ext_vector_type(2))) float fx2;

#define FIN 256
#define H1 4
#define CH 64
#define CAP 16384   // bucket capacity (avg fill 8.4K, sigma ~92)
#define G2S 40      // gemm2 LDS row stride (32 + 8 pad) -> 80B, 16B aligned

__device__ __forceinline__ float bf2f(ushort u) {
    union { unsigned int i; float f; } v; v.i = ((unsigned int)u) << 16; return v.f;
}
__device__ __forceinline__ ushort f2bf(float f) {
    union { float f; unsigned int i; } v; v.f = f;
    unsigned int r = v.i + 0x7fffu + ((v.i >> 16) & 1u);  // RNE
    return (ushort)(r >> 16);
}
__device__ __forceinline__ float load_in(const void* p, int i, int f) {
    return f ? ((const float*)p)[i] : bf2f(((const ushort*)p)[i]);
}
__device__ __forceinline__ int load_idx(const void* p, long long i, int f64) {
    return f64 ? (int)((const long long*)p)[i] : ((const int*)p)[i];
}

// packed-tile element offset for (row, k), K = 256 (KT = 8 k-tiles).
// tile = [16 rows][32 k]; lane (quad = (k>>3)&3, l16 = row&15) owns a
// contiguous 8-elem (16B) chunk.
__device__ __forceinline__ int pk_off(int row, int k, int KT) {
    return (((row >> 4) * KT + (k >> 5)) << 9) + (((k >> 3) & 3) << 7) +
           ((row & 15) << 3) + (k & 7);
}
// inverse (KT = 8): packed chunk base -> (row, k)
__device__ __forceinline__ void pk_dec(int po0, int& row, int& k) {
    int tile = po0 >> 9;
    row = ((tile >> 3) << 4) + ((po0 >> 3) & 15);
    k = ((tile & 7) << 5) + (((po0 >> 7) & 3) << 3);
}

// edge weight: leaky_relu(0.2) + exp
__device__ __forceinline__ float edge_p(float s) {
    s = fmaxf(s, 0.2f * s);
    return __expf(s);
}

// accumulate 16 bf16 channels (2x uint4) weighted by p into 8 packed f32 pairs
__device__ __forceinline__ void accum16(fx2* acc, uint4 v0, uint4 v1,
                                        float p, float& l) {
    l += p;
    fx2 pv = {p, p};
    unsigned w[8] = {v0.x, v0.y, v0.z, v0.w, v1.x, v1.y, v1.z, v1.w};
#pragma unroll
    for (int u = 0; u < 8; ++u) {
        union { unsigned i; float fl; } lo, hi;
        lo.i = w[u] << 16; hi.i = w[u] & 0xffff0000u;
        fx2 c = {lo.fl, hi.fl};
        acc[u] += pv * c;
    }
}

// accumulate 8 bf16 channels (uint4) weighted by p into 4 packed f32 pairs
__device__ __forceinline__ void accum8(fx2* acc, uint4 v, float p, float& l) {
    l += p;
    fx2 pv = {p, p};
    unsigned w[4] = {v.x, v.y, v.z, v.w};
#pragma unroll
    for (int u = 0; u < 4; ++u) {
        union { unsigned i; float fl; } lo, hi;
        lo.i = w[u] << 16; hi.i = w[u] & 0xffff0000u;
        fx2 c = {lo.fl, hi.fl};
        acc[u] += pv * c;
    }
}

// ---- dtype probe + bcnt zero ----------------------------------------------
__global__ __launch_bounds__(256) void probe_kernel(const ushort* __restrict__ x,
                                                    const int* __restrict__ ei,
                                                    int* __restrict__ flags,
                                                    int* __restrict__ bcnt) {
    __shared__ int s_nan, s_odd;
    int t = threadIdx.x;
    bcnt[t] = 0;
    if (t == 0) { s_nan = 0; s_odd = 0; }
    __syncthreads();
    int nanc = 0, oddc = 0;
    for (int i = t; i < 16384; i += 256) {
        ushort u = x[i];
        if (((u >> 7) & 0xFF) == 0xFF) nanc++;
    }
    for (int i = t; i < 2048; i += 256)
        if (ei[2 * i + 1] != 0) oddc++;
    if (nanc) atomicAdd(&s_nan, nanc);
    if (oddc) atomicAdd(&s_odd, oddc);
    __syncthreads();
    if (t == 0) {
        flags[0] = (s_nan >= 2) ? 1 : 0;  // 1 = floats are f32
        flags[1] = (s_odd == 0) ? 1 : 0;  // 1 = indices are int64
    }
}

// ---- fused: x pack (inverted) | W packs (inverted) | CSR bucket pass 1 -----
__global__ __launch_bounds__(256) void prep_bucket_kernel(
        const void* __restrict__ x, const void* __restrict__ W1,
        const void* __restrict__ W2, ushort* __restrict__ xb,
        ushort* __restrict__ Wt1, ushort* __restrict__ Wt2,
        const void* __restrict__ ei, int* __restrict__ bcnt,
        unsigned int* __restrict__ buckets,
        int E, int Etot, int Nn, const int* __restrict__ flags,
        int PB_conv, int PB_tr_end) {
    __shared__ int lcnt[256], lbase[256], lcur[256];
    int bid = blockIdx.x, t = threadIdx.x;
    int f = flags[0];
    if (bid < PB_conv) {      // ---- x -> packed bf16, one 16B chunk/thread
        int po0 = bid * 2048 + t * 8;
        int row, k0; pk_dec(po0, row, k0);
        int si = row * FIN + k0;
        if (f) {
            float4 v0 = ((const float4*)x)[si / 4];
            float4 v1 = ((const float4*)x)[si / 4 + 1];
            ushort4 o0, o1;
            o0.x = f2bf(v0.x); o0.y = f2bf(v0.y); o0.z = f2bf(v0.z); o0.w = f2bf(v0.w);
            o1.x = f2bf(v1.x); o1.y = f2bf(v1.y); o1.z = f2bf(v1.z); o1.w = f2bf(v1.w);
            *(ushort4*)(xb + po0) = o0;
            *(ushort4*)(xb + po0 + 4) = o1;
        } else {
            *(uint4*)(xb + po0) = ((const uint4*)x)[si / 8];
        }
        return;
    }
    if (bid < PB_tr_end) {    // ---- W1^T, W2^T packed, one chunk/thread
        int j = (bid - PB_conv) * 256 + t;
        if (j < (FIN * FIN) / 8) {
            int po0 = j * 8;
            int n, k0; pk_dec(po0, n, k0);
            ushort4 o0, o1;
            o0.x = f2bf(load_in(W1, (k0 + 0) * FIN + n, f));
            o0.y = f2bf(load_in(W1, (k0 + 1) * FIN + n, f));
            o0.z = f2bf(load_in(W1, (k0 + 2) * FIN + n, f));
            o0.w = f2bf(load_in(W1, (k0 + 3) * FIN + n, f));
            o1.x = f2bf(load_in(W1, (k0 + 4) * FIN + n, f));
            o1.y = f2bf(load_in(W1, (k0 + 5) * FIN + n, f));
            o1.z = f2bf(load_in(W1, (k0 + 6) * FIN + n, f));
            o1.w = f2bf(load_in(W1, (k0 + 7) * FIN + n, f));
            *(ushort4*)(Wt1 + po0) = o0;
            *(ushort4*)(Wt1 + po0 + 4) = o1;
        } else {
            int po0 = (j - (FIN * FIN) / 8) * 8;
            int n, k0; pk_dec(po0, n, k0);
            ushort4 o0, o1;
            o0.x = f2bf(load_in(W2, (k0 + 0) * CH + n, f));
            o0.y = f2bf(load_in(W2, (k0 + 1) * CH + n, f));
            o0.z = f2bf(load_in(W2, (k0 + 2) * CH + n, f));
            o0.w = f2bf(load_in(W2, (k0 + 3) * CH + n, f));
            o1.x = f2bf(load_in(W2, (k0 + 4) * CH + n, f));
            o1.y = f2bf(load_in(W2, (k0 + 5) * CH + n, f));
            o1.z = f2bf(load_in(W2, (k0 + 6) * CH + n, f));
            o1.w = f2bf(load_in(W2, (k0 + 7) * CH + n, f));
            *(ushort4*)(Wt2 + po0) = o0;
            *(ushort4*)(Wt2 + po0 + 4) = o1;
        }
        return;
    }
    // ---- CSR pass 1: bucket partition, 16 edges/thread (4096/block)
    lcnt[t] = 0; lcur[t] = 0;
    __syncthreads();
    int f64 = flags[1];
    int base = (bid - PB_tr_end) * 4096 + t;
    unsigned int val[16]; int bk[16]; bool ok[16];
#pragma unroll
    for (int j = 0; j < 16; ++j) {
        int e = base + j * 256;
        ok[j] = e < Etot;
        bk[j] = 0; val[j] = 0;
        if (ok[j]) {
            int s, d;
            if (e < E) {
                s = load_idx(ei, e, f64);
                d = load_idx(ei, (long long)E + e, f64);
            } else {
                s = d = e - E;   // self-loops appended
            }
            s = min(max(s, 0), Nn - 1);
            d = min(max(d, 0), Nn - 1);
            bk[j] = d >> 8;
            val[j] = ((unsigned int)s << 8) | (unsigned int)(d & 255);
            atomicAdd(&lcnt[bk[j]], 1);
        }
    }
    __syncthreads();
    if (lcnt[t] > 0) lbase[t] = atomicAdd(&bcnt[t], lcnt[t]);
    __syncthreads();
#pragma unroll
    for (int j = 0; j < 16; ++j) {
        if (ok[j]) {
            int p = lbase[bk[j]] + atomicAdd(&lcur[bk[j]], 1);
            if (p < CAP) buckets[(size_t)bk[j] * CAP + p] = val[j];
        }
    }
}

// ---- gemm1 core (MFMA bf16, packed operands, alpha fused, planar-128 C) ----
__device__ __forceinline__ void gemm_core(const ushort* __restrict__ A,
                                          const ushort* __restrict__ Bt,
                                          ushort* __restrict__ C,
                                          int M,
                                          const void* __restrict__ aS,
                                          const void* __restrict__ aD,
                                          float* __restrict__ alphaS,
                                          float* __restrict__ alphaD,
                                          int f, int gx, int head) {
    const int KT = FIN >> 5;   // 8 k-tiles
    int tid = threadIdx.x;
    int wave = tid >> 6, lane = tid & 63, quad = lane >> 4, l16 = lane & 15;
    int rbase = gx * 256 + wave * 64;
    int cbase = head * 64;
    int lsub = (quad << 7) + (l16 << 3);       // lane's chunk within a tile
    floatx4 acc[4][4];
#pragma unroll
    for (int i = 0; i < 4; i++)
#pragma unroll
        for (int j = 0; j < 4; j++) acc[i][j] = (floatx4)0.f;

#pragma unroll 2
    for (int kb = 0; kb < FIN; kb += 32) {
        int kt = kb >> 5;
        short8 a[4], b[4];
#pragma unroll
        for (int mt = 0; mt < 4; mt++) {
            int tr = (rbase + mt * 16) >> 4;
            a[mt] = *reinterpret_cast<const short8*>(
                A + (((size_t)(tr * KT + kt)) << 9) + lsub);
        }
#pragma unroll
        for (int nt = 0; nt < 4; nt++) {
            int tc = (cbase + nt * 16) >> 4;
            b[nt] = *reinterpret_cast<const short8*>(
                Bt + (((size_t)(tc * KT + kt)) << 9) + lsub);
        }
#pragma unroll
        for (int mt = 0; mt < 4; mt++)
#pragma unroll
            for (int nt = 0; nt < 4; nt++)
                acc[mt][nt] = __builtin_amdgcn_mfma_f32_16x16x32_bf16(
                    a[mt], b[nt], acc[mt][nt], 0, 0, 0);
    }
    float asv[4], adv[4];
#pragma unroll
    for (int nt = 0; nt < 4; nt++) {
        int col = cbase + nt * 16 + l16;
        asv[nt] = load_in(aS, col, f);
        adv[nt] = load_in(aD, col, f);
    }
    // C/D layout: col = lane&15, row = quad*4 + reg   [m89-verified]
#pragma unroll
    for (int mt = 0; mt < 4; mt++) {
#pragma unroll
        for (int r = 0; r < 4; r++) {
            int row = rbase + mt * 16 + quad * 4 + r;
            float ps = 0.f, pd = 0.f;
#pragma unroll
            for (int nt = 0; nt < 4; nt++) {
                float w = acc[mt][nt][r];
                ps += w * asv[nt];
                pd += w * adv[nt];
            }
#pragma unroll
            for (int off = 8; off > 0; off >>= 1) {  // reduce over 16 col-lanes
                ps += __shfl_xor(ps, off, 16);
                pd += __shfl_xor(pd, off, 16);
            }
            if (row < M) {
                if (l16 == 0) {
                    alphaS[row * H1 + head] = ps;
                    alphaD[row * H1 + head] = pd;
                }
#pragma unroll
                for (int nt = 0; nt < 4; nt++) {
                    int col = cbase + nt * 16 + l16;
                    size_t caddr = ((size_t)(col >> 7) * M + row) * 128 + (col & 127);
                    C[caddr] = f2bf(acc[mt][nt][r]);
                }
            }
        }
    }
}

// ---- fused: CSR pass-2 blocks [0, NB) + XCD-grouped gemm1 blocks -----------
// gemm1 map: gg = bid-NB; r = (gg&7) | ((gg>>5)<<3); h = (gg>>3)&3.
// All 4 heads of row-block r share bid mod 8 -> same XCD -> A fetched once
// per XCD; same-head blocks across row-groups also share XCD -> B resident.
__global__ __launch_bounds__(256) void gemm1_pass2_kernel(
        const ushort* __restrict__ A, const ushort* __restrict__ Bt,
        ushort* __restrict__ C, int M,
        const void* __restrict__ aS, const void* __restrict__ aD,
        float* __restrict__ alphaS, float* __restrict__ alphaD,
        const int* __restrict__ flags, int NB, int nbx,
        const int* __restrict__ bcnt, const unsigned int* __restrict__ buckets,
        int* __restrict__ offs, int* __restrict__ csr_src, int Nn) {
    __shared__ int part[256], sc[256], sc4[4][256];
    int bid = blockIdx.x;
    int t = threadIdx.x;
    if (bid >= NB) {
        int gg = bid - NB;
        int r = (gg & 7) | ((gg >> 5) << 3);
        int h = (gg >> 3) & 3;
        if (r < nbx)
            gemm_core(A, Bt, C, M, aS, aD, alphaS, alphaD, flags[0], r, h);
        return;
    }
    // ---- CSR pass 2: one block per 256-node bucket, wave-privatized ----
    int b = bid;
    int w = t >> 6;
    part[t] = bcnt[t];
    sc4[0][t] = 0; sc4[1][t] = 0; sc4[2][t] = 0; sc4[3][t] = 0;
    __syncthreads();
#pragma unroll
    for (int off = 1; off < 256; off <<= 1) {   // inclusive scan of bucket sizes
        int v = (t >= off) ? part[t - off] : 0;
        __syncthreads();
        part[t] += v;
        __syncthreads();
    }
    int basepos = (b == 0) ? 0 : part[b - 1];
    int nEdges = min(bcnt[b], CAP);
    const unsigned int* bk = buckets + (size_t)b * CAP;
    for (int i = t; i < nEdges; i += 256)       // private histogram per wave
        atomicAdd(&sc4[w][bk[i] & 255], 1);
    __syncthreads();
    int c0 = sc4[0][t], c1 = sc4[1][t], c2 = sc4[2][t], c3 = sc4[3][t];
    int mycount = c0 + c1 + c2 + c3;
    sc[t] = mycount;
    __syncthreads();
#pragma unroll
    for (int off = 1; off < 256; off <<= 1) {   // inclusive scan of node counts
        int v = (t >= off) ? sc[t - off] : 0;
        __syncthreads();
        sc[t] += v;
        __syncthreads();
    }
    int excl = sc[t] - mycount;
    int gnode = b * 256 + t;
    if (gnode <= Nn) offs[gnode] = basepos + excl;
    // cursors = node base + exclusive wave base (same wave assignment below)
    sc4[0][t] = excl;
    sc4[1][t] = excl + c0;
    sc4[2][t] = excl + c0 + c1;
    sc4[3][t] = excl + c0 + c1 + c2;
    __syncthreads();
    for (int i = t; i < nEdges; i += 256) {
        unsigned int v = bk[i];
        int p = atomicAdd(&sc4[w][v & 255], 1);
        csr_src[basepos + p] = (int)(v >> 8);
    }
}

// ---- layer-2 gemm (H=1), LDS-staged A (hmidb row-major [M][256]) -----------
// Per k-step: stage A[256][32] into LDS (4 rounds, 4 threads/row -> 16
// lines/wave-instr), pad rows to G2S=40 elems (2-way bank alias = free).
__global__ __launch_bounds__(256) void gemm2_kernel(const ushort* __restrict__ A,
                                                    const ushort* __restrict__ Bt,
                                                    ushort* __restrict__ C,
                                                    int M,
                                                    const void* __restrict__ aS,
                                                    const void* __restrict__ aD,
                                                    float* __restrict__ alphaS,
                                                    float* __restrict__ alphaD,
                                                    const int* __restrict__ flags) {
    __shared__ ushort Asub[256 * G2S];          // 20 KB
    const int KT = FIN >> 5;
    int t = threadIdx.x;
    int f = flags[0];
    int wave = t >> 6, lane = t & 63, quad = lane >> 4, l16 = lane & 15;
    int rbase = blockIdx.x * 256 + wave * 64;
    int lsub = (quad << 7) + (l16 << 3);
    int chunk = t & 3, rr = t >> 2;             // staging map: 4 thr/row
    floatx4 acc[4][4];
#pragma unroll
    for (int i = 0; i < 4; i++)
#pragma unroll
        for (int j = 0; j < 4; j++) acc[i][j] = (floatx4)0.f;

    for (int kb = 0; kb < FIN; kb += 32) {
        __syncthreads();                        // prior reads done
#pragma unroll
        for (int rd = 0; rd < 4; ++rd) {
            int row = blockIdx.x * 256 + rd * 64 + rr;
            if (row >= M) row = M - 1;
            uint4 v = *(const uint4*)(A + (size_t)row * FIN + kb + chunk * 8);
            *(uint4*)(Asub + (rd * 64 + rr) * G2S + chunk * 8) = v;
        }
        __syncthreads();
        int kt = kb >> 5;
        short8 b[4];
#pragma unroll
        for (int nt = 0; nt < 4; nt++) {
            b[nt] = *reinterpret_cast<const short8*>(
                Bt + (((size_t)(nt * KT + kt)) << 9) + lsub);
        }
#pragma unroll
        for (int mt = 0; mt < 4; mt++) {
            short8 a = *reinterpret_cast<const short8*>(
                Asub + (wave * 64 + mt * 16 + l16) * G2S + quad * 8);
#pragma unroll
            for (int nt = 0; nt < 4; nt++)
                acc[mt][nt] = __builtin_amdgcn_mfma_f32_16x16x32_bf16(
                    a, b[nt], acc[mt][nt], 0, 0, 0);
        }
    }
    float asv[4], adv[4];
#pragma unroll
    for (int nt = 0; nt < 4; nt++) {
        int col = nt * 16 + l16;
        asv[nt] = load_in(aS, col, f);
        adv[nt] = load_in(aD, col, f);
    }
#pragma unroll
    for (int mt = 0; mt < 4; mt++) {
#pragma unroll
        for (int r = 0; r < 4; r++) {
            int row = rbase + mt * 16 + quad * 4 + r;
            float ps = 0.f, pd = 0.f;
#pragma unroll
            for (int nt = 0; nt < 4; nt++) {
                float w = acc[mt][nt][r];
                ps += w * asv[nt];
                pd += w * adv[nt];
            }
#pragma unroll
            for (int off = 8; off > 0; off >>= 1) {
                ps += __shfl_xor(ps, off, 16);
                pd += __shfl_xor(pd, off, 16);
            }
            if (row < M) {
                if (l16 == 0) {
                    alphaS[row] = ps;
                    alphaD[row] = pd;
                }
#pragma unroll
                for (int nt = 0; nt < 4; nt++) {
                    int col = nt * 16 + l16;
                    C[(size_t)row * CH + col] = f2bf(acc[mt][nt][r]);
                }
            }
        }
    }
}

// ---- layer-1 aggregation, one plane (128 ch) per dispatch ------------------
// 1 wave/node, 8 edge slots (slot=lane>>3) x 8 ch-groups (cg=lane&7, 16ch).
// 16-edge granule (r9 structure -- measured best); masked tail via p=0.
// Epilogue: ROW-MAJOR hmidb (coalesced; r9's 12.5MB WRITE). csr loads NT.
__global__ __launch_bounds__(256) void gat_node1_pass(
        const int* __restrict__ csr_src, const int* __restrict__ offs,
        const float* __restrict__ asrc, const float* __restrict__ adst,
        const ushort* __restrict__ h1p, const void* __restrict__ b1,
        ushort* __restrict__ hmidb, int Nn, const int* __restrict__ flags,
        int plane) {
    int f = flags[0];
    int wave = threadIdx.x >> 6, lane = threadIdx.x & 63;
    int n = blockIdx.x * 4 + wave;
    if (n >= Nn) return;
    int slot = lane >> 3, cg = lane & 7;       // 8 edge slots x 8 ch-groups
    int head = plane * 2 + (cg >> 2);
    float ad = adst[n * H1 + head];
    unsigned rowbase = (unsigned)(plane * Nn) * 128u + (unsigned)cg * 16u;
    int beg = offs[n], end = offs[n + 1];
    fx2 acc[8];
#pragma unroll
    for (int u = 0; u < 8; ++u) acc[u] = (fx2)0.f;
    float l = 0.f;

    int e = beg;
    while (e + 16 <= end) {                    // full granule, no masks
        int sa = __builtin_nontemporal_load(csr_src + e + slot);
        int sb = __builtin_nontemporal_load(csr_src + e + 8 + slot);
        float aa = asrc[sa * H1 + head];
        float ab = asrc[sb * H1 + head];
        const uint4* ra = (const uint4*)(h1p + rowbase + (unsigned)sa * 128u);
        const uint4* rb = (const uint4*)(h1p + rowbase + (unsigned)sb * 128u);
        uint4 va0 = ra[0], va1 = ra[1];
        uint4 vb0 = rb[0], vb1 = rb[1];
        float pa = edge_p(aa + ad);
        float pb = edge_p(ab + ad);
        accum16(acc, va0, va1, pa, l);
        accum16(acc, vb0, vb1, pb, l);
        e += 16;
    }
    if (e < end) {                             // masked tail (<16 edges)
        int ea = e + slot, eb = e + 8 + slot;
        bool oka = ea < end, okb = eb < end;
        int sa = csr_src[oka ? ea : beg];
        int sb = csr_src[okb ? eb : beg];
        float aa = asrc[sa * H1 + head];
        float ab = asrc[sb * H1 + head];
        const uint4* ra = (const uint4*)(h1p + rowbase + (unsigned)sa * 128u);
        const uint4* rb = (const uint4*)(h1p + rowbase + (unsigned)sb * 128u);
        uint4 va0 = ra[0], va1 = ra[1];
        uint4 vb0 = rb[0], vb1 = rb[1];
        float pa = edge_p(oka ? aa + ad : -1e30f);   // p = 0 when masked
        float pb = edge_p(okb ? ab + ad : -1e30f);
        accum16(acc, va0, va1, pa, l);
        accum16(acc, vb0, vb1, pb, l);
    }
    // reduce across the 8 edge slots (lane bits 3..5)
#pragma unroll
    for (int off = 8; off <= 32; off <<= 1) {
#pragma unroll
        for (int u = 0; u < 8; ++u) {
            acc[u][0] += __shfl_xor(acc[u][0], off);
            acc[u][1] += __shfl_xor(acc[u][1], off);
        }
        l += __shfl_xor(l, off);
    }
    if (slot == 0) {
        float inv = 1.f / (l + 1e-16f);
        int cb = plane * 128 + cg * 16;
        unsigned ow[8];
#pragma unroll
        for (int u = 0; u < 8; ++u) {
            float o0 = acc[u][0] * inv + load_in(b1, cb + 2 * u, f);
            float o1 = acc[u][1] * inv + load_in(b1, cb + 2 * u + 1, f);
            o0 = o0 > 0.f ? o0 : __expf(o0) - 1.f;   // ELU
            o1 = o1 > 0.f ? o1 : __expf(o1) - 1.f;
            ow[u] = (unsigned)f2bf(o0) | ((unsigned)f2bf(o1) << 16);
        }
        uint4 st0, st1;
        st0.x = ow[0]; st0.y = ow[1]; st0.z = ow[2]; st0.w = ow[3];
        st1.x = ow[4]; st1.y = ow[5]; st1.z = ow[6]; st1.w = ow[7];
        uint4* dst = (uint4*)(hmidb + (size_t)n * 256 + cb);
        dst[0] = st0; dst[1] = st1;
    }
}

// ---- layer-2 aggregation: 1 wave/node, 8 edge slots x 8ch (uint4/lane) -----
__global__ __launch_bounds__(256) void gat_node2(const int* __restrict__ csr_src,
                                                 const int* __restrict__ offs,
                                                 const float* __restrict__ asrc,
                                                 const float* __restrict__ adst,
                                                 const ushort* __restrict__ h2b,
                                                 const void* __restrict__ b2,
                                                 void* __restrict__ out, int Nn,
                                                 const int* __restrict__ flags) {
    int f = flags[0];
    int wave = threadIdx.x >> 6, lane = threadIdx.x & 63;
    int n = blockIdx.x * 4 + wave;
    if (n >= Nn) return;
    int slot = lane >> 3, cg = lane & 7;
    float ad = adst[n];
    unsigned rowoff = (unsigned)cg * 8u;
    int beg = offs[n], end = offs[n + 1];
    fx2 acc[4];
#pragma unroll
    for (int u = 0; u < 4; ++u) acc[u] = (fx2)0.f;
    float l = 0.f;

    int e = beg;
    while (e + 16 <= end) {                    // full granule
        int sa = __builtin_nontemporal_load(csr_src + e + slot);
        int sb = __builtin_nontemporal_load(csr_src + e + 8 + slot);
        float aa = asrc[sa];
        float ab = asrc[sb];
        uint4 va = *(const uint4*)(h2b + rowoff + (unsigned)sa * 64u);
        uint4 vb = *(const uint4*)(h2b + rowoff + (unsigned)sb * 64u);
        float pa = edge_p(aa + ad);
        float pb = edge_p(ab + ad);
        accum8(acc, va, pa, l);
        accum8(acc, vb, pb, l);
        e += 16;
    }
    if (e < end) {                             // masked tail
        int ea = e + slot, eb = e + 8 + slot;
        bool oka = ea < end, okb = eb < end;
        int sa = csr_src[oka ? ea : beg];
        int sb = csr_src[okb ? eb : beg];
        float aa = asrc[sa];
        float ab = asrc[sb];
        uint4 va = *(const uint4*)(h2b + rowoff + (unsigned)sa * 64u);
        uint4 vb = *(const uint4*)(h2b + rowoff + (unsigned)sb * 64u);
        float pa = edge_p(oka ? aa + ad : -1e30f);
        float pb = edge_p(okb ? ab + ad : -1e30f);
        accum8(acc, va, pa, l);
        accum8(acc, vb, pb, l);
    }
#pragma unroll
    for (int off = 8; off <= 32; off <<= 1) {
#pragma unroll
        for (int u = 0; u < 4; ++u) {
            acc[u][0] += __shfl_xor(acc[u][0], off);
            acc[u][1] += __shfl_xor(acc[u][1], off);
        }
        l += __shfl_xor(l, off);
    }
    if (slot == 0) {
        float inv = 1.f / (l + 1e-16f);
        float o[8];
#pragma unroll
        for (int u = 0; u < 4; ++u) {
            o[2 * u]     = acc[u][0] * inv + load_in(b2, cg * 8 + 2 * u, f);
            o[2 * u + 1] = acc[u][1] * inv + load_in(b2, cg * 8 + 2 * u + 1, f);
        }
        if (f) {
            float* op = (float*)out + (unsigned)n * 64u + (unsigned)cg * 8u;
            float4 s0, s1;
            s0.x = o[0]; s0.y = o[1]; s0.z = o[2]; s0.w = o[3];
            s1.x = o[4]; s1.y = o[5]; s1.z = o[6]; s1.w = o[7];
            *(float4*)op = s0;
            *(float4*)(op + 4) = s1;
        } else {
            uint4 st;
            st.x = (unsigned)f2bf(o[0]) | ((unsigned)f2bf(o[1]) << 16);
            st.y = (unsigned)f2bf(o[2]) | ((unsigned)f2bf(o[3]) << 16);
            st.z = (unsigned)f2bf(o[4]) | ((unsigned)f2bf(o[5]) << 16);
            st.w = (unsigned)f2bf(o[6]) | ((unsigned)f2bf(o[7]) << 16);
            *(uint4*)((ushort*)out + (unsigned)n * 64u + (unsigned)cg * 8u) = st;
        }
    }
}

extern "C" void kernel_launch(void* const* d_in, const int* in_sizes, int n_in,
                              void* d_out, int out_size, void* d_ws, size_t ws_size,
                              hipStream_t stream) {
    const void* x   = d_in[0];
    const void* ei  = d_in[1];
    const void* W1  = d_in[2];
    const void* as1 = d_in[3];
    const void* ad1 = d_in[4];
    const void* b1  = d_in[5];
    const void* W2  = d_in[6];
    const void* as2 = d_in[7];
    const void* ad2 = d_in[8];
    const void* b2  = d_in[9];

    const int Nn = in_sizes[0] / FIN;      // 50000
    const int E  = in_sizes[1] / 2;        // 1600000
    const int ET = E + Nn;
    const int NB = (Nn + 255) >> 8;        // 196 buckets

    char* ws = (char*)d_ws;
    size_t off = 0;
    auto alloc = [&](size_t bytes) {
        size_t o = off;
        off += (bytes + 255) & ~(size_t)255;
        return o;
    };
    ushort* xb    = (ushort*)(ws + alloc((size_t)Nn * FIN * 2));   // packed tiles
    ushort* h1b   = (ushort*)(ws + alloc((size_t)Nn * FIN * 2));   // planar [2][Nn][128]
    ushort* hmidb = (ushort*)(ws + alloc((size_t)Nn * FIN * 2));   // row-major [Nn][256]
    ushort* h2b   = (ushort*)(ws + alloc((size_t)Nn * CH * 2));    // row-major [Nn][64]
    ushort* Wt1   = (ushort*)(ws + alloc((size_t)FIN * FIN * 2));  // packed tiles
    ushort* Wt2   = (ushort*)(ws + alloc((size_t)CH * FIN * 2));   // packed tiles
    float* as1f   = (float*)(ws + alloc((size_t)Nn * H1 * 4));
    float* ad1f   = (float*)(ws + alloc((size_t)Nn * H1 * 4));
    float* as2f   = (float*)(ws + alloc((size_t)Nn * 4));
    float* ad2f   = (float*)(ws + alloc((size_t)Nn * 4));
    int*   offs   = (int*)(ws + alloc((size_t)(Nn + 1) * 4));
    int*   csr    = (int*)(ws + alloc((size_t)ET * 4));
    unsigned int* buckets = (unsigned int*)(ws + alloc((size_t)256 * CAP * 4));
    int*   bcnt   = (int*)(ws + alloc(256 * 4));
    int*   flags  = (int*)(ws + alloc(256));
    (void)ws_size; (void)n_in; (void)out_size;

    probe_kernel<<<1, 256, 0, stream>>>((const ushort*)x, (const int*)ei, flags, bcnt);

    // fused prep (pack x, W1^T, W2^T) | bucket pass 1
    int PB_conv = (Nn * FIN) / 2048;                       // one 16B chunk/thread
    int PB_tr   = (FIN * FIN + CH * FIN) / 2048;           // 40
    int PB_bkt  = (ET + 4095) / 4096;
    prep_bucket_kernel<<<PB_conv + PB_tr + PB_bkt, 256, 0, stream>>>(
        x, W1, W2, xb, Wt1, Wt2, ei, bcnt, buckets,
        E, ET, Nn, flags, PB_conv, PB_conv + PB_tr);

    // fused: CSR pass 2 (first) + XCD-grouped gemm1 (+alpha, planar-128 C)
    int nbx = (Nn + 255) / 256;            // 196 row-blocks
    int ngrp = (nbx + 7) >> 3;             // 25 row-groups of 8
    gemm1_pass2_kernel<<<NB + ngrp * 32, 256, 0, stream>>>(
        xb, Wt1, h1b, Nn, as1, ad1, as1f, ad1f,
        flags, NB, nbx, bcnt, buckets, offs, csr, Nn);

    // layer-1 aggregation: one dispatch per 128-ch plane (time-separated)
    gat_node1_pass<<<(Nn + 3) / 4, 256, 0, stream>>>(
        csr, offs, as1f, ad1f, h1b, b1, hmidb, Nn, flags, 0);
    gat_node1_pass<<<(Nn + 3) / 4, 256, 0, stream>>>(
        csr, offs, as1f, ad1f, h1b, b1, hmidb, Nn, flags, 1);

    // layer 2
    gemm2_kernel<<<(Nn + 255) / 256, 256, 0, stream>>>(
        hmidb, Wt2, h2b, Nn, as2, ad2, as2f, ad2f, flags);
    gat_node2<<<(Nn + 3) / 4, 256, 0, stream>>>(csr, offs, as2f, ad2f, h2b, b2, d_out, Nn, flags);
}

// Round 8
// 344.756 us; speedup vs baseline: 1.0408x; 1.0408x over previous
//
#include <hip/hip_runtime.h>

// ---------------------------------------------------------------------------
// GAT encoder, 2 layers, MI355X — round 16 (r15 compile-fixed).
// Dtype-adaptive (probe: f32-vs-bf16 floats, i64-vs-i32 indices).
// bf16 internal, f32 accumulation, direct-sum softmax (logits bounded).
// Ledger of measured lessons:
//  r7  : interleaving both h1 planes doubles FETCH — keep 2 per-plane node1
//        dispatches (hard footprint separation).
//  r9  : node1 8 edges/wave 16-granule = 59.3us/pass. Structure floor:
//        r9/r11/r13 all pin 59-61us @ ~3.1 TB/s L2-miss service.
//  r10 : 32-ch slice passes regress (replicated streams / ~40us fixed cost
//        per pass). gemm1_pass2 55us was the PASS2 TAIL, not gemm-bound.
//  r11 : packed gemm operands fix scattered fragment loads; node1 packed
//        epilogue costs +3us/pass (keep row-major hmidb).
//  r12 : 32-edge granule: VGPR 52, occupancy 37%, node1 74us. REVERTED.
//  r13 : pass2-first + wave-privatized counting sort: 354.5us BEST.
//  r14 : NT *loads* on csr: FETCH +4.2MB (line reuse lost), node1 +2.5us.
//        REVERTED. XCD gemm1 map + gemm2 LDS kept (not implicated).
//  r15 : __builtin_nontemporal_store needs ext_vector types, not
//        HIP_vector_type (uint4/float4) -> compile fail. Fixed here.
// r16: plain csr loads; NT *stores* (via ext-vector uintx4/floatx4) for
// write-once outputs (hmidb in node1, out in node2) so they stop evicting
// the gather plane from L2.
// 7 dispatches: probe, prep+bucket, pass2+gemm1, node1 x2, gemm2, node2.
// ---------------------------------------------------------------------------

typedef __attribute__((ext_vector_type(8))) short short8;
typedef __attribute__((ext_vector_type(4))) float floatx4;
typedef __attribute__((ext_vector_type(2))) float fx2;
typedef __attribute__((ext_vector_type(4))) unsigned int uintx4;

#define FIN 256
#define H1 4
#define CH 64
#define CAP 16384   // bucket capacity (avg fill 8.4K, sigma ~92)
#define G2S 40      // gemm2 LDS row stride (32 + 8 pad) -> 80B, 16B aligned

__device__ __forceinline__ float bf2f(ushort u) {
    union { unsigned int i; float f; } v; v.i = ((unsigned int)u) << 16; return v.f;
}
__device__ __forceinline__ ushort f2bf(float f) {
    union { float f; unsigned int i; } v; v.f = f;
    unsigned int r = v.i + 0x7fffu + ((v.i >> 16) & 1u);  // RNE
    return (ushort)(r >> 16);
}
__device__ __forceinline__ float load_in(const void* p, int i, int f) {
    return f ? ((const float*)p)[i] : bf2f(((const ushort*)p)[i]);
}
__device__ __forceinline__ int load_idx(const void* p, long long i, int f64) {
    return f64 ? (int)((const long long*)p)[i] : ((const int*)p)[i];
}

// packed-tile element offset for (row, k), K = 256 (KT = 8 k-tiles).
// tile = [16 rows][32 k]; lane (quad = (k>>3)&3, l16 = row&15) owns a
// contiguous 8-elem (16B) chunk.
__device__ __forceinline__ int pk_off(int row, int k, int KT) {
    return (((row >> 4) * KT + (k >> 5)) << 9) + (((k >> 3) & 3) << 7) +
           ((row & 15) << 3) + (k & 7);
}
// inverse (KT = 8): packed chunk base -> (row, k)
__device__ __forceinline__ void pk_dec(int po0, int& row, int& k) {
    int tile = po0 >> 9;
    row = ((tile >> 3) << 4) + ((po0 >> 3) & 15);
    k = ((tile & 7) << 5) + (((po0 >> 7) & 3) << 3);
}

// edge weight: leaky_relu(0.2) + exp
__device__ __forceinline__ float edge_p(float s) {
    s = fmaxf(s, 0.2f * s);
    return __expf(s);
}

// accumulate 16 bf16 channels (2x uint4) weighted by p into 8 packed f32 pairs
__device__ __forceinline__ void accum16(fx2* acc, uint4 v0, uint4 v1,
                                        float p, float& l) {
    l += p;
    fx2 pv = {p, p};
    unsigned w[8] = {v0.x, v0.y, v0.z, v0.w, v1.x, v1.y, v1.z, v1.w};
#pragma unroll
    for (int u = 0; u < 8; ++u) {
        union { unsigned i; float fl; } lo, hi;
        lo.i = w[u] << 16; hi.i = w[u] & 0xffff0000u;
        fx2 c = {lo.fl, hi.fl};
        acc[u] += pv * c;
    }
}

// accumulate 8 bf16 channels (uint4) weighted by p into 4 packed f32 pairs
__device__ __forceinline__ void accum8(fx2* acc, uint4 v, float p, float& l) {
    l += p;
    fx2 pv = {p, p};
    unsigned w[4] = {v.x, v.y, v.z, v.w};
#pragma unroll
    for (int u = 0; u < 4; ++u) {
        union { unsigned i; float fl; } lo, hi;
        lo.i = w[u] << 16; hi.i = w[u] & 0xffff0000u;
        fx2 c = {lo.fl, hi.fl};
        acc[u] += pv * c;
    }
}

// ---- dtype probe + bcnt zero ----------------------------------------------
__global__ __launch_bounds__(256) void probe_kernel(const ushort* __restrict__ x,
                                                    const int* __restrict__ ei,
                                                    int* __restrict__ flags,
                                                    int* __restrict__ bcnt) {
    __shared__ int s_nan, s_odd;
    int t = threadIdx.x;
    bcnt[t] = 0;
    if (t == 0) { s_nan = 0; s_odd = 0; }
    __syncthreads();
    int nanc = 0, oddc = 0;
    for (int i = t; i < 16384; i += 256) {
        ushort u = x[i];
        if (((u >> 7) & 0xFF) == 0xFF) nanc++;
    }
    for (int i = t; i < 2048; i += 256)
        if (ei[2 * i + 1] != 0) oddc++;
    if (nanc) atomicAdd(&s_nan, nanc);
    if (oddc) atomicAdd(&s_odd, oddc);
    __syncthreads();
    if (t == 0) {
        flags[0] = (s_nan >= 2) ? 1 : 0;  // 1 = floats are f32
        flags[1] = (s_odd == 0) ? 1 : 0;  // 1 = indices are int64
    }
}

// ---- fused: x pack (inverted) | W packs (inverted) | CSR bucket pass 1 -----
__global__ __launch_bounds__(256) void prep_bucket_kernel(
        const void* __restrict__ x, const void* __restrict__ W1,
        const void* __restrict__ W2, ushort* __restrict__ xb,
        ushort* __restrict__ Wt1, ushort* __restrict__ Wt2,
        const void* __restrict__ ei, int* __restrict__ bcnt,
        unsigned int* __restrict__ buckets,
        int E, int Etot, int Nn, const int* __restrict__ flags,
        int PB_conv, int PB_tr_end) {
    __shared__ int lcnt[256], lbase[256], lcur[256];
    int bid = blockIdx.x, t = threadIdx.x;
    int f = flags[0];
    if (bid < PB_conv) {      // ---- x -> packed bf16, one 16B chunk/thread
        int po0 = bid * 2048 + t * 8;
        int row, k0; pk_dec(po0, row, k0);
        int si = row * FIN + k0;
        if (f) {
            float4 v0 = ((const float4*)x)[si / 4];
            float4 v1 = ((const float4*)x)[si / 4 + 1];
            ushort4 o0, o1;
            o0.x = f2bf(v0.x); o0.y = f2bf(v0.y); o0.z = f2bf(v0.z); o0.w = f2bf(v0.w);
            o1.x = f2bf(v1.x); o1.y = f2bf(v1.y); o1.z = f2bf(v1.z); o1.w = f2bf(v1.w);
            *(ushort4*)(xb + po0) = o0;
            *(ushort4*)(xb + po0 + 4) = o1;
        } else {
            *(uint4*)(xb + po0) = ((const uint4*)x)[si / 8];
        }
        return;
    }
    if (bid < PB_tr_end) {    // ---- W1^T, W2^T packed, one chunk/thread
        int j = (bid - PB_conv) * 256 + t;
        if (j < (FIN * FIN) / 8) {
            int po0 = j * 8;
            int n, k0; pk_dec(po0, n, k0);
            ushort4 o0, o1;
            o0.x = f2bf(load_in(W1, (k0 + 0) * FIN + n, f));
            o0.y = f2bf(load_in(W1, (k0 + 1) * FIN + n, f));
            o0.z = f2bf(load_in(W1, (k0 + 2) * FIN + n, f));
            o0.w = f2bf(load_in(W1, (k0 + 3) * FIN + n, f));
            o1.x = f2bf(load_in(W1, (k0 + 4) * FIN + n, f));
            o1.y = f2bf(load_in(W1, (k0 + 5) * FIN + n, f));
            o1.z = f2bf(load_in(W1, (k0 + 6) * FIN + n, f));
            o1.w = f2bf(load_in(W1, (k0 + 7) * FIN + n, f));
            *(ushort4*)(Wt1 + po0) = o0;
            *(ushort4*)(Wt1 + po0 + 4) = o1;
        } else {
            int po0 = (j - (FIN * FIN) / 8) * 8;
            int n, k0; pk_dec(po0, n, k0);
            ushort4 o0, o1;
            o0.x = f2bf(load_in(W2, (k0 + 0) * CH + n, f));
            o0.y = f2bf(load_in(W2, (k0 + 1) * CH + n, f));
            o0.z = f2bf(load_in(W2, (k0 + 2) * CH + n, f));
            o0.w = f2bf(load_in(W2, (k0 + 3) * CH + n, f));
            o1.x = f2bf(load_in(W2, (k0 + 4) * CH + n, f));
            o1.y = f2bf(load_in(W2, (k0 + 5) * CH + n, f));
            o1.z = f2bf(load_in(W2, (k0 + 6) * CH + n, f));
            o1.w = f2bf(load_in(W2, (k0 + 7) * CH + n, f));
            *(ushort4*)(Wt2 + po0) = o0;
            *(ushort4*)(Wt2 + po0 + 4) = o1;
        }
        return;
    }
    // ---- CSR pass 1: bucket partition, 16 edges/thread (4096/block)
    lcnt[t] = 0; lcur[t] = 0;
    __syncthreads();
    int f64 = flags[1];
    int base = (bid - PB_tr_end) * 4096 + t;
    unsigned int val[16]; int bk[16]; bool ok[16];
#pragma unroll
    for (int j = 0; j < 16; ++j) {
        int e = base + j * 256;
        ok[j] = e < Etot;
        bk[j] = 0; val[j] = 0;
        if (ok[j]) {
            int s, d;
            if (e < E) {
                s = load_idx(ei, e, f64);
                d = load_idx(ei, (long long)E + e, f64);
            } else {
                s = d = e - E;   // self-loops appended
            }
            s = min(max(s, 0), Nn - 1);
            d = min(max(d, 0), Nn - 1);
            bk[j] = d >> 8;
            val[j] = ((unsigned int)s << 8) | (unsigned int)(d & 255);
            atomicAdd(&lcnt[bk[j]], 1);
        }
    }
    __syncthreads();
    if (lcnt[t] > 0) lbase[t] = atomicAdd(&bcnt[t], lcnt[t]);
    __syncthreads();
#pragma unroll
    for (int j = 0; j < 16; ++j) {
        if (ok[j]) {
            int p = lbase[bk[j]] + atomicAdd(&lcur[bk[j]], 1);
            if (p < CAP) buckets[(size_t)bk[j] * CAP + p] = val[j];
        }
    }
}

// ---- gemm1 core (MFMA bf16, packed operands, alpha fused, planar-128 C) ----
__device__ __forceinline__ void gemm_core(const ushort* __restrict__ A,
                                          const ushort* __restrict__ Bt,
                                          ushort* __restrict__ C,
                                          int M,
                                          const void* __restrict__ aS,
                                          const void* __restrict__ aD,
                                          float* __restrict__ alphaS,
                                          float* __restrict__ alphaD,
                                          int f, int gx, int head) {
    const int KT = FIN >> 5;   // 8 k-tiles
    int tid = threadIdx.x;
    int wave = tid >> 6, lane = tid & 63, quad = lane >> 4, l16 = lane & 15;
    int rbase = gx * 256 + wave * 64;
    int cbase = head * 64;
    int lsub = (quad << 7) + (l16 << 3);       // lane's chunk within a tile
    floatx4 acc[4][4];
#pragma unroll
    for (int i = 0; i < 4; i++)
#pragma unroll
        for (int j = 0; j < 4; j++) acc[i][j] = (floatx4)0.f;

#pragma unroll 2
    for (int kb = 0; kb < FIN; kb += 32) {
        int kt = kb >> 5;
        short8 a[4], b[4];
#pragma unroll
        for (int mt = 0; mt < 4; mt++) {
            int tr = (rbase + mt * 16) >> 4;
            a[mt] = *reinterpret_cast<const short8*>(
                A + (((size_t)(tr * KT + kt)) << 9) + lsub);
        }
#pragma unroll
        for (int nt = 0; nt < 4; nt++) {
            int tc = (cbase + nt * 16) >> 4;
            b[nt] = *reinterpret_cast<const short8*>(
                Bt + (((size_t)(tc * KT + kt)) << 9) + lsub);
        }
#pragma unroll
        for (int mt = 0; mt < 4; mt++)
#pragma unroll
            for (int nt = 0; nt < 4; nt++)
                acc[mt][nt] = __builtin_amdgcn_mfma_f32_16x16x32_bf16(
                    a[mt], b[nt], acc[mt][nt], 0, 0, 0);
    }
    float asv[4], adv[4];
#pragma unroll
    for (int nt = 0; nt < 4; nt++) {
        int col = cbase + nt * 16 + l16;
        asv[nt] = load_in(aS, col, f);
        adv[nt] = load_in(aD, col, f);
    }
    // C/D layout: col = lane&15, row = quad*4 + reg   [m89-verified]
#pragma unroll
    for (int mt = 0; mt < 4; mt++) {
#pragma unroll
        for (int r = 0; r < 4; r++) {
            int row = rbase + mt * 16 + quad * 4 + r;
            float ps = 0.f, pd = 0.f;
#pragma unroll
            for (int nt = 0; nt < 4; nt++) {
                float w = acc[mt][nt][r];
                ps += w * asv[nt];
                pd += w * adv[nt];
            }
#pragma unroll
            for (int off = 8; off > 0; off >>= 1) {  // reduce over 16 col-lanes
                ps += __shfl_xor(ps, off, 16);
                pd += __shfl_xor(pd, off, 16);
            }
            if (row < M) {
                if (l16 == 0) {
                    alphaS[row * H1 + head] = ps;
                    alphaD[row * H1 + head] = pd;
                }
#pragma unroll
                for (int nt = 0; nt < 4; nt++) {
                    int col = cbase + nt * 16 + l16;
                    size_t caddr = ((size_t)(col >> 7) * M + row) * 128 + (col & 127);
                    C[caddr] = f2bf(acc[mt][nt][r]);
                }
            }
        }
    }
}

// ---- fused: CSR pass-2 blocks [0, NB) + XCD-grouped gemm1 blocks -----------
// gemm1 map: gg = bid-NB; r = (gg&7) | ((gg>>5)<<3); h = (gg>>3)&3.
// All 4 heads of row-block r share bid mod 8 -> same XCD -> A fetched once
// per XCD; same-head blocks across row-groups also share XCD -> B resident.
__global__ __launch_bounds__(256) void gemm1_pass2_kernel(
        const ushort* __restrict__ A, const ushort* __restrict__ Bt,
        ushort* __restrict__ C, int M,
        const void* __restrict__ aS, const void* __restrict__ aD,
        float* __restrict__ alphaS, float* __restrict__ alphaD,
        const int* __restrict__ flags, int NB, int nbx,
        const int* __restrict__ bcnt, const unsigned int* __restrict__ buckets,
        int* __restrict__ offs, int* __restrict__ csr_src, int Nn) {
    __shared__ int part[256], sc[256], sc4[4][256];
    int bid = blockIdx.x;
    int t = threadIdx.x;
    if (bid >= NB) {
        int gg = bid - NB;
        int r = (gg & 7) | ((gg >> 5) << 3);
        int h = (gg >> 3) & 3;
        if (r < nbx)
            gemm_core(A, Bt, C, M, aS, aD, alphaS, alphaD, flags[0], r, h);
        return;
    }
    // ---- CSR pass 2: one block per 256-node bucket, wave-privatized ----
    int b = bid;
    int w = t >> 6;
    part[t] = bcnt[t];
    sc4[0][t] = 0; sc4[1][t] = 0; sc4[2][t] = 0; sc4[3][t] = 0;
    __syncthreads();
#pragma unroll
    for (int off = 1; off < 256; off <<= 1) {   // inclusive scan of bucket sizes
        int v = (t >= off) ? part[t - off] : 0;
        __syncthreads();
        part[t] += v;
        __syncthreads();
    }
    int basepos = (b == 0) ? 0 : part[b - 1];
    int nEdges = min(bcnt[b], CAP);
    const unsigned int* bk = buckets + (size_t)b * CAP;
    for (int i = t; i < nEdges; i += 256)       // private histogram per wave
        atomicAdd(&sc4[w][bk[i] & 255], 1);
    __syncthreads();
    int c0 = sc4[0][t], c1 = sc4[1][t], c2 = sc4[2][t], c3 = sc4[3][t];
    int mycount = c0 + c1 + c2 + c3;
    sc[t] = mycount;
    __syncthreads();
#pragma unroll
    for (int off = 1; off < 256; off <<= 1) {   // inclusive scan of node counts
        int v = (t >= off) ? sc[t - off] : 0;
        __syncthreads();
        sc[t] += v;
        __syncthreads();
    }
    int excl = sc[t] - mycount;
    int gnode = b * 256 + t;
    if (gnode <= Nn) offs[gnode] = basepos + excl;
    // cursors = node base + exclusive wave base (same wave assignment below)
    sc4[0][t] = excl;
    sc4[1][t] = excl + c0;
    sc4[2][t] = excl + c0 + c1;
    sc4[3][t] = excl + c0 + c1 + c2;
    __syncthreads();
    for (int i = t; i < nEdges; i += 256) {
        unsigned int v = bk[i];
        int p = atomicAdd(&sc4[w][v & 255], 1);
        csr_src[basepos + p] = (int)(v >> 8);
    }
}

// ---- layer-2 gemm (H=1), LDS-staged A (hmidb row-major [M][256]) -----------
__global__ __launch_bounds__(256) void gemm2_kernel(const ushort* __restrict__ A,
                                                    const ushort* __restrict__ Bt,
                                                    ushort* __restrict__ C,
                                                    int M,
                                                    const void* __restrict__ aS,
                                                    const void* __restrict__ aD,
                                                    float* __restrict__ alphaS,
                                                    float* __restrict__ alphaD,
                                                    const int* __restrict__ flags) {
    __shared__ ushort Asub[256 * G2S];          // 20 KB
    const int KT = FIN >> 5;
    int t = threadIdx.x;
    int f = flags[0];
    int wave = t >> 6, lane = t & 63, quad = lane >> 4, l16 = lane & 15;
    int rbase = blockIdx.x * 256 + wave * 64;
    int lsub = (quad << 7) + (l16 << 3);
    int chunk = t & 3, rr = t >> 2;             // staging map: 4 thr/row
    floatx4 acc[4][4];
#pragma unroll
    for (int i = 0; i < 4; i++)
#pragma unroll
        for (int j = 0; j < 4; j++) acc[i][j] = (floatx4)0.f;

    for (int kb = 0; kb < FIN; kb += 32) {
        __syncthreads();                        // prior reads done
#pragma unroll
        for (int rd = 0; rd < 4; ++rd) {
            int row = blockIdx.x * 256 + rd * 64 + rr;
            if (row >= M) row = M - 1;
            uint4 v = *(const uint4*)(A + (size_t)row * FIN + kb + chunk * 8);
            *(uint4*)(Asub + (rd * 64 + rr) * G2S + chunk * 8) = v;
        }
        __syncthreads();
        int kt = kb >> 5;
        short8 b[4];
#pragma unroll
        for (int nt = 0; nt < 4; nt++) {
            b[nt] = *reinterpret_cast<const short8*>(
                Bt + (((size_t)(nt * KT + kt)) << 9) + lsub);
        }
#pragma unroll
        for (int mt = 0; mt < 4; mt++) {
            short8 a = *reinterpret_cast<const short8*>(
                Asub + (wave * 64 + mt * 16 + l16) * G2S + quad * 8);
#pragma unroll
            for (int nt = 0; nt < 4; nt++)
                acc[mt][nt] = __builtin_amdgcn_mfma_f32_16x16x32_bf16(
                    a, b[nt], acc[mt][nt], 0, 0, 0);
        }
    }
    float asv[4], adv[4];
#pragma unroll
    for (int nt = 0; nt < 4; nt++) {
        int col = nt * 16 + l16;
        asv[nt] = load_in(aS, col, f);
        adv[nt] = load_in(aD, col, f);
    }
#pragma unroll
    for (int mt = 0; mt < 4; mt++) {
#pragma unroll
        for (int r = 0; r < 4; r++) {
            int row = rbase + mt * 16 + quad * 4 + r;
            float ps = 0.f, pd = 0.f;
#pragma unroll
            for (int nt = 0; nt < 4; nt++) {
                float w = acc[mt][nt][r];
                ps += w * asv[nt];
                pd += w * adv[nt];
            }
#pragma unroll
            for (int off = 8; off > 0; off >>= 1) {
                ps += __shfl_xor(ps, off, 16);
                pd += __shfl_xor(pd, off, 16);
            }
            if (row < M) {
                if (l16 == 0) {
                    alphaS[row] = ps;
                    alphaD[row] = pd;
                }
#pragma unroll
                for (int nt = 0; nt < 4; nt++) {
                    int col = nt * 16 + l16;
                    C[(size_t)row * CH + col] = f2bf(acc[mt][nt][r]);
                }
            }
        }
    }
}

// ---- layer-1 aggregation, one plane (128 ch) per dispatch ------------------
// 1 wave/node, 8 edge slots (slot=lane>>3) x 8 ch-groups (cg=lane&7, 16ch).
// 16-edge granule (r9 structure -- measured best); masked tail via p=0.
// Plain csr loads (r14 NT-load regression reverted). Epilogue: ROW-MAJOR
// hmidb via NT stores (ext-vector; write-once, stop evicting h1p lines).
__global__ __launch_bounds__(256) void gat_node1_pass(
        const int* __restrict__ csr_src, const int* __restrict__ offs,
        const float* __restrict__ asrc, const float* __restrict__ adst,
        const ushort* __restrict__ h1p, const void* __restrict__ b1,
        ushort* __restrict__ hmidb, int Nn, const int* __restrict__ flags,
        int plane) {
    int f = flags[0];
    int wave = threadIdx.x >> 6, lane = threadIdx.x & 63;
    int n = blockIdx.x * 4 + wave;
    if (n >= Nn) return;
    int slot = lane >> 3, cg = lane & 7;       // 8 edge slots x 8 ch-groups
    int head = plane * 2 + (cg >> 2);
    float ad = adst[n * H1 + head];
    unsigned rowbase = (unsigned)(plane * Nn) * 128u + (unsigned)cg * 16u;
    int beg = offs[n], end = offs[n + 1];
    fx2 acc[8];
#pragma unroll
    for (int u = 0; u < 8; ++u) acc[u] = (fx2)0.f;
    float l = 0.f;

    int e = beg;
    while (e + 16 <= end) {                    // full granule, no masks
        int sa = csr_src[e + slot];
        int sb = csr_src[e + 8 + slot];
        float aa = asrc[sa * H1 + head];
        float ab = asrc[sb * H1 + head];
        const uint4* ra = (const uint4*)(h1p + rowbase + (unsigned)sa * 128u);
        const uint4* rb = (const uint4*)(h1p + rowbase + (unsigned)sb * 128u);
        uint4 va0 = ra[0], va1 = ra[1];
        uint4 vb0 = rb[0], vb1 = rb[1];
        float pa = edge_p(aa + ad);
        float pb = edge_p(ab + ad);
        accum16(acc, va0, va1, pa, l);
        accum16(acc, vb0, vb1, pb, l);
        e += 16;
    }
    if (e < end) {                             // masked tail (<16 edges)
        int ea = e + slot, eb = e + 8 + slot;
        bool oka = ea < end, okb = eb < end;
        int sa = csr_src[oka ? ea : beg];
        int sb = csr_src[okb ? eb : beg];
        float aa = asrc[sa * H1 + head];
        float ab = asrc[sb * H1 + head];
        const uint4* ra = (const uint4*)(h1p + rowbase + (unsigned)sa * 128u);
        const uint4* rb = (const uint4*)(h1p + rowbase + (unsigned)sb * 128u);
        uint4 va0 = ra[0], va1 = ra[1];
        uint4 vb0 = rb[0], vb1 = rb[1];
        float pa = edge_p(oka ? aa + ad : -1e30f);   // p = 0 when masked
        float pb = edge_p(okb ? ab + ad : -1e30f);
        accum16(acc, va0, va1, pa, l);
        accum16(acc, vb0, vb1, pb, l);
    }
    // reduce across the 8 edge slots (lane bits 3..5)
#pragma unroll
    for (int off = 8; off <= 32; off <<= 1) {
#pragma unroll
        for (int u = 0; u < 8; ++u) {
            acc[u][0] += __shfl_xor(acc[u][0], off);
            acc[u][1] += __shfl_xor(acc[u][1], off);
        }
        l += __shfl_xor(l, off);
    }
    if (slot == 0) {
        float inv = 1.f / (l + 1e-16f);
        int cb = plane * 128 + cg * 16;
        unsigned ow[8];
#pragma unroll
        for (int u = 0; u < 8; ++u) {
            float o0 = acc[u][0] * inv + load_in(b1, cb + 2 * u, f);
            float o1 = acc[u][1] * inv + load_in(b1, cb + 2 * u + 1, f);
            o0 = o0 > 0.f ? o0 : __expf(o0) - 1.f;   // ELU
            o1 = o1 > 0.f ? o1 : __expf(o1) - 1.f;
            ow[u] = (unsigned)f2bf(o0) | ((unsigned)f2bf(o1) << 16);
        }
        uintx4 st0 = {ow[0], ow[1], ow[2], ow[3]};
        uintx4 st1 = {ow[4], ow[5], ow[6], ow[7]};
        uintx4* dst = (uintx4*)(hmidb + (size_t)n * 256 + cb);
        __builtin_nontemporal_store(st0, dst);
        __builtin_nontemporal_store(st1, dst + 1);
    }
}

// ---- layer-2 aggregation: 1 wave/node, 8 edge slots x 8ch (uint4/lane) -----
// Plain csr loads; NT stores (ext-vector) for out (write-once, never re-read).
__global__ __launch_bounds__(256) void gat_node2(const int* __restrict__ csr_src,
                                                 const int* __restrict__ offs,
                                                 const float* __restrict__ asrc,
                                                 const float* __restrict__ adst,
                                                 const ushort* __restrict__ h2b,
                                                 const void* __restrict__ b2,
                                                 void* __restrict__ out, int Nn,
                                                 const int* __restrict__ flags) {
    int f = flags[0];
    int wave = threadIdx.x >> 6, lane = threadIdx.x & 63;
    int n = blockIdx.x * 4 + wave;
    if (n >= Nn) return;
    int slot = lane >> 3, cg = lane & 7;
    float ad = adst[n];
    unsigned rowoff = (unsigned)cg * 8u;
    int beg = offs[n], end = offs[n + 1];
    fx2 acc[4];
#pragma unroll
    for (int u = 0; u < 4; ++u) acc[u] = (fx2)0.f;
    float l = 0.f;

    int e = beg;
    while (e + 16 <= end) {                    // full granule
        int sa = csr_src[e + slot];
        int sb = csr_src[e + 8 + slot];
        float aa = asrc[sa];
        float ab = asrc[sb];
        uint4 va = *(const uint4*)(h2b + rowoff + (unsigned)sa * 64u);
        uint4 vb = *(const uint4*)(h2b + rowoff + (unsigned)sb * 64u);
        float pa = edge_p(aa + ad);
        float pb = edge_p(ab + ad);
        accum8(acc, va, pa, l);
        accum8(acc, vb, pb, l);
        e += 16;
    }
    if (e < end) {                             // masked tail
        int ea = e + slot, eb = e + 8 + slot;
        bool oka = ea < end, okb = eb < end;
        int sa = csr_src[oka ? ea : beg];
        int sb = csr_src[okb ? eb : beg];
        float aa = asrc[sa];
        float ab = asrc[sb];
        uint4 va = *(const uint4*)(h2b + rowoff + (unsigned)sa * 64u);
        uint4 vb = *(const uint4*)(h2b + rowoff + (unsigned)sb * 64u);
        float pa = edge_p(oka ? aa + ad : -1e30f);
        float pb = edge_p(okb ? ab + ad : -1e30f);
        accum8(acc, va, pa, l);
        accum8(acc, vb, pb, l);
    }
#pragma unroll
    for (int off = 8; off <= 32; off <<= 1) {
#pragma unroll
        for (int u = 0; u < 4; ++u) {
            acc[u][0] += __shfl_xor(acc[u][0], off);
            acc[u][1] += __shfl_xor(acc[u][1], off);
        }
        l += __shfl_xor(l, off);
    }
    if (slot == 0) {
        float inv = 1.f / (l + 1e-16f);
        float o[8];
#pragma unroll
        for (int u = 0; u < 4; ++u) {
            o[2 * u]     = acc[u][0] * inv + load_in(b2, cg * 8 + 2 * u, f);
            o[2 * u + 1] = acc[u][1] * inv + load_in(b2, cg * 8 + 2 * u + 1, f);
        }
        if (f) {
            float* op = (float*)out + (unsigned)n * 64u + (unsigned)cg * 8u;
            floatx4 s0 = {o[0], o[1], o[2], o[3]};
            floatx4 s1 = {o[4], o[5], o[6], o[7]};
            __builtin_nontemporal_store(s0, (floatx4*)op);
            __builtin_nontemporal_store(s1, (floatx4*)(op + 4));
        } else {
            uintx4 st = {(unsigned)f2bf(o[0]) | ((unsigned)f2bf(o[1]) << 16),
                         (unsigned)f2bf(o[2]) | ((unsigned)f2bf(o[3]) << 16),
                         (unsigned)f2bf(o[4]) | ((unsigned)f2bf(o[5]) << 16),
                         (unsigned)f2bf(o[6]) | ((unsigned)f2bf(o[7]) << 16)};
            __builtin_nontemporal_store(st,
                (uintx4*)((ushort*)out + (unsigned)n * 64u + (unsigned)cg * 8u));
        }
    }
}

extern "C" void kernel_launch(void* const* d_in, const int* in_sizes, int n_in,
                              void* d_out, int out_size, void* d_ws, size_t ws_size,
                              hipStream_t stream) {
    const void* x   = d_in[0];
    const void* ei  = d_in[1];
    const void* W1  = d_in[2];
    const void* as1 = d_in[3];
    const void* ad1 = d_in[4];
    const void* b1  = d_in[5];
    const void* W2  = d_in[6];
    const void* as2 = d_in[7];
    const void* ad2 = d_in[8];
    const void* b2  = d_in[9];

    const int Nn = in_sizes[0] / FIN;      // 50000
    const int E  = in_sizes[1] / 2;        // 1600000
    const int ET = E + Nn;
    const int NB = (Nn + 255) >> 8;        // 196 buckets

    char* ws = (char*)d_ws;
    size_t off = 0;
    auto alloc = [&](size_t bytes) {
        size_t o = off;
        off += (bytes + 255) & ~(size_t)255;
        return o;
    };
    ushort* xb    = (ushort*)(ws + alloc((size_t)Nn * FIN * 2));   // packed tiles
    ushort* h1b   = (ushort*)(ws + alloc((size_t)Nn * FIN * 2));   // planar [2][Nn][128]
    ushort* hmidb = (ushort*)(ws + alloc((size_t)Nn * FIN * 2));   // row-major [Nn][256]
    ushort* h2b   = (ushort*)(ws + alloc((size_t)Nn * CH * 2));    // row-major [Nn][64]
    ushort* Wt1   = (ushort*)(ws + alloc((size_t)FIN * FIN * 2));  // packed tiles
    ushort* Wt2   = (ushort*)(ws + alloc((size_t)CH * FIN * 2));   // packed tiles
    float* as1f   = (float*)(ws + alloc((size_t)Nn * H1 * 4));
    float* ad1f   = (float*)(ws + alloc((size_t)Nn * H1 * 4));
    float* as2f   = (float*)(ws + alloc((size_t)Nn * 4));
    float* ad2f   = (float*)(ws + alloc((size_t)Nn * 4));
    int*   offs   = (int*)(ws + alloc((size_t)(Nn + 1) * 4));
    int*   csr    = (int*)(ws + alloc((size_t)ET * 4));
    unsigned int* buckets = (unsigned int*)(ws + alloc((size_t)256 * CAP * 4));
    int*   bcnt   = (int*)(ws + alloc(256 * 4));
    int*   flags  = (int*)(ws + alloc(256));
    (void)ws_size; (void)n_in; (void)out_size;

    probe_kernel<<<1, 256, 0, stream>>>((const ushort*)x, (const int*)ei, flags, bcnt);

    // fused prep (pack x, W1^T, W2^T) | bucket pass 1
    int PB_conv = (Nn * FIN) / 2048;                       // one 16B chunk/thread
    int PB_tr   = (FIN * FIN + CH * FIN) / 2048;           // 40
    int PB_bkt  = (ET + 4095) / 4096;
    prep_bucket_kernel<<<PB_conv + PB_tr + PB_bkt, 256, 0, stream>>>(
        x, W1, W2, xb, Wt1, Wt2, ei, bcnt, buckets,
        E, ET, Nn, flags, PB_conv, PB_conv + PB_tr);

    // fused: CSR pass 2 (first) + XCD-grouped gemm1 (+alpha, planar-128 C)
    int nbx = (Nn + 255) / 256;            // 196 row-blocks
    int ngrp = (nbx + 7) >> 3;             // 25 row-groups of 8
    gemm1_pass2_kernel<<<NB + ngrp * 32, 256, 0, stream>>>(
        xb, Wt1, h1b, Nn, as1, ad1, as1f, ad1f,
        flags, NB, nbx, bcnt, buckets, offs, csr, Nn);

    // layer-1 aggregation: one dispatch per 128-ch plane (time-separated)
    gat_node1_pass<<<(Nn + 3) / 4, 256, 0, stream>>>(
        csr, offs, as1f, ad1f, h1b, b1, hmidb, Nn, flags, 0);
    gat_node1_pass<<<(Nn + 3) / 4, 256, 0, stream>>>(
        csr, offs, as1f, ad1f, h1b, b1, hmidb, Nn, flags, 1);

    // layer 2
    gemm2_kernel<<<(Nn + 255) / 256, 256, 0, stream>>>(
        hmidb, Wt2, h2b, Nn, as2, ad2, as2f, ad2f, flags);
    gat_node2<<<(Nn + 3) / 4, 256, 0, stream>>>(csr, offs, as2f, ad2f, h2b, b2, d_out, Nn, flags);
}

// Round 9
// 333.783 us; speedup vs baseline: 1.0750x; 1.0329x over previous
//
#include <hip/hip_runtime.h>

// ---------------------------------------------------------------------------
// GAT encoder, 2 layers, MI355X — round 17.
// Dtype-adaptive (probe: f32-vs-bf16 floats, i64-vs-i32 indices).
// bf16 internal, f32 accumulation, direct-sum softmax (logits bounded).
// Ledger of measured lessons:
//  r7  : interleaving both h1 planes doubles FETCH — keep 2 per-plane node1
//        dispatches (hard footprint separation).
//  r9  : node1 8 edges/wave 16-granule = 59.3us/pass. Structure floor:
//        r9/r11/r13/r16 all pin 59-61us @ ~3.1 TB/s L2-miss service.
//  r10 : 32-ch slice passes regress (replicated streams). gemm1_pass2 55us
//        was the PASS2 TAIL, not gemm-bound.
//  r11 : packed gemm operands fix scattered fragment loads; node1 packed
//        epilogue costs +3us/pass (keep row-major hmidb).
//  r12 : 32-edge granule: VGPR 52, occupancy 37%, node1 74us. REVERTED.
//  r13 : pass2-first + wave-privatized counting sort: 354.5us.
//  r14 : NT *loads* on csr: FETCH +4.2MB (line reuse lost). REVERTED.
//  r16 : NT *stores* on write-once outputs: 344.8us BEST. node1 FETCH
//        173.7MB. NT-store steering is real (write-once only!).
// r17: (a) probe vectorized (uint4; was 64 scalar ushort iters/thread —
// single-block latency); (b) bench inputs are bf16 (npz arithmetic): skip
// x-repack when f==0, gemm1 LDS-stages A from raw row-major x per k-step
// (gemm2's proven staging pattern); f==1 keeps packed-xb path.
// 7 dispatches: probe, prep+bucket, pass2+gemm1, node1 x2, gemm2, node2.
// ---------------------------------------------------------------------------

typedef __attribute__((ext_vector_type(8))) short short8;
typedef __attribute__((ext_vector_type(4))) float floatx4;
typedef __attribute__((ext_vector_type(2))) float fx2;
typedef __attribute__((ext_vector_type(4))) unsigned int uintx4;

#define FIN 256
#define H1 4
#define CH 64
#define CAP 16384   // bucket capacity (avg fill 8.4K, sigma ~92)
#define G2S 40      // LDS A-stage row stride (32 + 8 pad) -> 80B, 16B aligned

__device__ __forceinline__ float bf2f(ushort u) {
    union { unsigned int i; float f; } v; v.i = ((unsigned int)u) << 16; return v.f;
}
__device__ __forceinline__ ushort f2bf(float f) {
    union { float f; unsigned int i; } v; v.f = f;
    unsigned int r = v.i + 0x7fffu + ((v.i >> 16) & 1u);  // RNE
    return (ushort)(r >> 16);
}
__device__ __forceinline__ float load_in(const void* p, int i, int f) {
    return f ? ((const float*)p)[i] : bf2f(((const ushort*)p)[i]);
}
__device__ __forceinline__ int load_idx(const void* p, long long i, int f64) {
    return f64 ? (int)((const long long*)p)[i] : ((const int*)p)[i];
}

// packed-tile element offset for (row, k), K = 256 (KT = 8 k-tiles).
__device__ __forceinline__ int pk_off(int row, int k, int KT) {
    return (((row >> 4) * KT + (k >> 5)) << 9) + (((k >> 3) & 3) << 7) +
           ((row & 15) << 3) + (k & 7);
}
// inverse (KT = 8): packed chunk base -> (row, k)
__device__ __forceinline__ void pk_dec(int po0, int& row, int& k) {
    int tile = po0 >> 9;
    row = ((tile >> 3) << 4) + ((po0 >> 3) & 15);
    k = ((tile & 7) << 5) + (((po0 >> 7) & 3) << 3);
}

// edge weight: leaky_relu(0.2) + exp
__device__ __forceinline__ float edge_p(float s) {
    s = fmaxf(s, 0.2f * s);
    return __expf(s);
}

// accumulate 16 bf16 channels (2x uint4) weighted by p into 8 packed f32 pairs
__device__ __forceinline__ void accum16(fx2* acc, uint4 v0, uint4 v1,
                                        float p, float& l) {
    l += p;
    fx2 pv = {p, p};
    unsigned w[8] = {v0.x, v0.y, v0.z, v0.w, v1.x, v1.y, v1.z, v1.w};
#pragma unroll
    for (int u = 0; u < 8; ++u) {
        union { unsigned i; float fl; } lo, hi;
        lo.i = w[u] << 16; hi.i = w[u] & 0xffff0000u;
        fx2 c = {lo.fl, hi.fl};
        acc[u] += pv * c;
    }
}

// accumulate 8 bf16 channels (uint4) weighted by p into 4 packed f32 pairs
__device__ __forceinline__ void accum8(fx2* acc, uint4 v, float p, float& l) {
    l += p;
    fx2 pv = {p, p};
    unsigned w[4] = {v.x, v.y, v.z, v.w};
#pragma unroll
    for (int u = 0; u < 4; ++u) {
        union { unsigned i; float fl; } lo, hi;
        lo.i = w[u] << 16; hi.i = w[u] & 0xffff0000u;
        fx2 c = {lo.fl, hi.fl};
        acc[u] += pv * c;
    }
}

// ---- dtype probe (vectorized) + bcnt zero ---------------------------------
// x nan check: 16384 ushorts as 1024 uint4 (4/thread). ei i64 check: first
// 4096 int32 words as 1024 uint4 (odd words .y/.w must be 0 for i64).
__global__ __launch_bounds__(256) void probe_kernel(const uint4* __restrict__ x4,
                                                    const uint4* __restrict__ ei4,
                                                    int* __restrict__ flags,
                                                    int* __restrict__ bcnt) {
    __shared__ int s_nan, s_odd;
    int t = threadIdx.x;
    bcnt[t] = 0;
    if (t == 0) { s_nan = 0; s_odd = 0; }
    __syncthreads();
    int nanc = 0, oddc = 0;
#pragma unroll
    for (int j = 0; j < 4; ++j) {
        uint4 v = x4[t * 4 + j];
        unsigned w[4] = {v.x, v.y, v.z, v.w};
#pragma unroll
        for (int u = 0; u < 4; ++u) {
            if (((w[u] >> 7) & 0xFFu) == 0xFFu) nanc++;    // low ushort
            if (((w[u] >> 23) & 0xFFu) == 0xFFu) nanc++;   // high ushort
        }
    }
#pragma unroll
    for (int j = 0; j < 4; ++j) {
        uint4 v = ei4[t * 4 + j];
        if (v.y != 0u) oddc++;
        if (v.w != 0u) oddc++;
    }
    if (nanc) atomicAdd(&s_nan, nanc);
    if (oddc) atomicAdd(&s_odd, oddc);
    __syncthreads();
    if (t == 0) {
        flags[0] = (s_nan >= 2) ? 1 : 0;  // 1 = floats are f32
        flags[1] = (s_odd == 0) ? 1 : 0;  // 1 = indices are int64
    }
}

// ---- fused: x pack (f32 only) | W packs | CSR bucket pass 1 ----------------
__global__ __launch_bounds__(256) void prep_bucket_kernel(
        const void* __restrict__ x, const void* __restrict__ W1,
        const void* __restrict__ W2, ushort* __restrict__ xb,
        ushort* __restrict__ Wt1, ushort* __restrict__ Wt2,
        const void* __restrict__ ei, int* __restrict__ bcnt,
        unsigned int* __restrict__ buckets,
        int E, int Etot, int Nn, const int* __restrict__ flags,
        int PB_conv, int PB_tr_end) {
    __shared__ int lcnt[256], lbase[256], lcur[256];
    int bid = blockIdx.x, t = threadIdx.x;
    int f = flags[0];
    if (bid < PB_conv) {      // ---- x -> packed bf16 (only needed when f32;
        if (!f) return;       //      bf16 input is read raw by gemm1)
        int po0 = bid * 2048 + t * 8;
        int row, k0; pk_dec(po0, row, k0);
        int si = row * FIN + k0;
        float4 v0 = ((const float4*)x)[si / 4];
        float4 v1 = ((const float4*)x)[si / 4 + 1];
        ushort4 o0, o1;
        o0.x = f2bf(v0.x); o0.y = f2bf(v0.y); o0.z = f2bf(v0.z); o0.w = f2bf(v0.w);
        o1.x = f2bf(v1.x); o1.y = f2bf(v1.y); o1.z = f2bf(v1.z); o1.w = f2bf(v1.w);
        *(ushort4*)(xb + po0) = o0;
        *(ushort4*)(xb + po0 + 4) = o1;
        return;
    }
    if (bid < PB_tr_end) {    // ---- W1^T, W2^T packed, one chunk/thread
        int j = (bid - PB_conv) * 256 + t;
        if (j < (FIN * FIN) / 8) {
            int po0 = j * 8;
            int n, k0; pk_dec(po0, n, k0);
            ushort4 o0, o1;
            o0.x = f2bf(load_in(W1, (k0 + 0) * FIN + n, f));
            o0.y = f2bf(load_in(W1, (k0 + 1) * FIN + n, f));
            o0.z = f2bf(load_in(W1, (k0 + 2) * FIN + n, f));
            o0.w = f2bf(load_in(W1, (k0 + 3) * FIN + n, f));
            o1.x = f2bf(load_in(W1, (k0 + 4) * FIN + n, f));
            o1.y = f2bf(load_in(W1, (k0 + 5) * FIN + n, f));
            o1.z = f2bf(load_in(W1, (k0 + 6) * FIN + n, f));
            o1.w = f2bf(load_in(W1, (k0 + 7) * FIN + n, f));
            *(ushort4*)(Wt1 + po0) = o0;
            *(ushort4*)(Wt1 + po0 + 4) = o1;
        } else {
            int po0 = (j - (FIN * FIN) / 8) * 8;
            int n, k0; pk_dec(po0, n, k0);
            ushort4 o0, o1;
            o0.x = f2bf(load_in(W2, (k0 + 0) * CH + n, f));
            o0.y = f2bf(load_in(W2, (k0 + 1) * CH + n, f));
            o0.z = f2bf(load_in(W2, (k0 + 2) * CH + n, f));
            o0.w = f2bf(load_in(W2, (k0 + 3) * CH + n, f));
            o1.x = f2bf(load_in(W2, (k0 + 4) * CH + n, f));
            o1.y = f2bf(load_in(W2, (k0 + 5) * CH + n, f));
            o1.z = f2bf(load_in(W2, (k0 + 6) * CH + n, f));
            o1.w = f2bf(load_in(W2, (k0 + 7) * CH + n, f));
            *(ushort4*)(Wt2 + po0) = o0;
            *(ushort4*)(Wt2 + po0 + 4) = o1;
        }
        return;
    }
    // ---- CSR pass 1: bucket partition, 16 edges/thread (4096/block)
    lcnt[t] = 0; lcur[t] = 0;
    __syncthreads();
    int f64 = flags[1];
    int base = (bid - PB_tr_end) * 4096 + t;
    unsigned int val[16]; int bk[16]; bool ok[16];
#pragma unroll
    for (int j = 0; j < 16; ++j) {
        int e = base + j * 256;
        ok[j] = e < Etot;
        bk[j] = 0; val[j] = 0;
        if (ok[j]) {
            int s, d;
            if (e < E) {
                s = load_idx(ei, e, f64);
                d = load_idx(ei, (long long)E + e, f64);
            } else {
                s = d = e - E;   // self-loops appended
            }
            s = min(max(s, 0), Nn - 1);
            d = min(max(d, 0), Nn - 1);
            bk[j] = d >> 8;
            val[j] = ((unsigned int)s << 8) | (unsigned int)(d & 255);
            atomicAdd(&lcnt[bk[j]], 1);
        }
    }
    __syncthreads();
    if (lcnt[t] > 0) lbase[t] = atomicAdd(&bcnt[t], lcnt[t]);
    __syncthreads();
#pragma unroll
    for (int j = 0; j < 16; ++j) {
        if (ok[j]) {
            int p = lbase[bk[j]] + atomicAdd(&lcur[bk[j]], 1);
            if (p < CAP) buckets[(size_t)bk[j] * CAP + p] = val[j];
        }
    }
}

// ---- gemm1 core (MFMA bf16, alpha fused, planar-128 C) ---------------------
// A source: f==1 -> packed xb tiles; f==0 -> LDS-staged from raw row-major
// bf16 x (gemm2's staging pattern). Bt always packed.
__device__ __forceinline__ void gemm_core(const ushort* __restrict__ Axb,
                                          const ushort* __restrict__ Xraw,
                                          ushort* __restrict__ Asub,
                                          const ushort* __restrict__ Bt,
                                          ushort* __restrict__ C,
                                          int M,
                                          const void* __restrict__ aS,
                                          const void* __restrict__ aD,
                                          float* __restrict__ alphaS,
                                          float* __restrict__ alphaD,
                                          int f, int gx, int head) {
    const int KT = FIN >> 5;   // 8 k-tiles
    int tid = threadIdx.x;
    int wave = tid >> 6, lane = tid & 63, quad = lane >> 4, l16 = lane & 15;
    int rbase = gx * 256 + wave * 64;
    int cbase = head * 64;
    int lsub = (quad << 7) + (l16 << 3);       // lane's chunk within a tile
    floatx4 acc[4][4];
#pragma unroll
    for (int i = 0; i < 4; i++)
#pragma unroll
        for (int j = 0; j < 4; j++) acc[i][j] = (floatx4)0.f;

    if (f) {                                   // packed xb path
#pragma unroll 2
        for (int kb = 0; kb < FIN; kb += 32) {
            int kt = kb >> 5;
            short8 a[4], b[4];
#pragma unroll
            for (int mt = 0; mt < 4; mt++) {
                int tr = (rbase + mt * 16) >> 4;
                a[mt] = *reinterpret_cast<const short8*>(
                    Axb + (((size_t)(tr * KT + kt)) << 9) + lsub);
            }
#pragma unroll
            for (int nt = 0; nt < 4; nt++) {
                int tc = (cbase + nt * 16) >> 4;
                b[nt] = *reinterpret_cast<const short8*>(
                    Bt + (((size_t)(tc * KT + kt)) << 9) + lsub);
            }
#pragma unroll
            for (int mt = 0; mt < 4; mt++)
#pragma unroll
                for (int nt = 0; nt < 4; nt++)
                    acc[mt][nt] = __builtin_amdgcn_mfma_f32_16x16x32_bf16(
                        a[mt], b[nt], acc[mt][nt], 0, 0, 0);
        }
    } else {                                   // LDS-staged raw-x path
        int chunk = tid & 3, rr = tid >> 2;    // 4 thr/row
        for (int kb = 0; kb < FIN; kb += 32) {
            __syncthreads();
#pragma unroll
            for (int rd = 0; rd < 4; ++rd) {
                int row = gx * 256 + rd * 64 + rr;
                if (row >= M) row = M - 1;
                uint4 v = *(const uint4*)(Xraw + (size_t)row * FIN + kb + chunk * 8);
                *(uint4*)(Asub + (rd * 64 + rr) * G2S + chunk * 8) = v;
            }
            __syncthreads();
            int kt = kb >> 5;
            short8 b[4];
#pragma unroll
            for (int nt = 0; nt < 4; nt++) {
                int tc = (cbase + nt * 16) >> 4;
                b[nt] = *reinterpret_cast<const short8*>(
                    Bt + (((size_t)(tc * KT + kt)) << 9) + lsub);
            }
#pragma unroll
            for (int mt = 0; mt < 4; mt++) {
                short8 a = *reinterpret_cast<const short8*>(
                    Asub + (wave * 64 + mt * 16 + l16) * G2S + quad * 8);
#pragma unroll
                for (int nt = 0; nt < 4; nt++)
                    acc[mt][nt] = __builtin_amdgcn_mfma_f32_16x16x32_bf16(
                        a, b[nt], acc[mt][nt], 0, 0, 0);
            }
        }
    }
    float asv[4], adv[4];
#pragma unroll
    for (int nt = 0; nt < 4; nt++) {
        int col = cbase + nt * 16 + l16;
        asv[nt] = load_in(aS, col, f);
        adv[nt] = load_in(aD, col, f);
    }
    // C/D layout: col = lane&15, row = quad*4 + reg   [m89-verified]
#pragma unroll
    for (int mt = 0; mt < 4; mt++) {
#pragma unroll
        for (int r = 0; r < 4; r++) {
            int row = rbase + mt * 16 + quad * 4 + r;
            float ps = 0.f, pd = 0.f;
#pragma unroll
            for (int nt = 0; nt < 4; nt++) {
                float w = acc[mt][nt][r];
                ps += w * asv[nt];
                pd += w * adv[nt];
            }
#pragma unroll
            for (int off = 8; off > 0; off >>= 1) {  // reduce over 16 col-lanes
                ps += __shfl_xor(ps, off, 16);
                pd += __shfl_xor(pd, off, 16);
            }
            if (row < M) {
                if (l16 == 0) {
                    alphaS[row * H1 + head] = ps;
                    alphaD[row * H1 + head] = pd;
                }
#pragma unroll
                for (int nt = 0; nt < 4; nt++) {
                    int col = cbase + nt * 16 + l16;
                    size_t caddr = ((size_t)(col >> 7) * M + row) * 128 + (col & 127);
                    C[caddr] = f2bf(acc[mt][nt][r]);
                }
            }
        }
    }
}

// ---- fused: CSR pass-2 blocks [0, NB) + XCD-grouped gemm1 blocks -----------
__global__ __launch_bounds__(256) void gemm1_pass2_kernel(
        const ushort* __restrict__ Axb, const ushort* __restrict__ Xraw,
        const ushort* __restrict__ Bt,
        ushort* __restrict__ C, int M,
        const void* __restrict__ aS, const void* __restrict__ aD,
        float* __restrict__ alphaS, float* __restrict__ alphaD,
        const int* __restrict__ flags, int NB, int nbx,
        const int* __restrict__ bcnt, const unsigned int* __restrict__ buckets,
        int* __restrict__ offs, int* __restrict__ csr_src, int Nn) {
    __shared__ int part[256], sc[256], sc4[4][256];
    __shared__ ushort Asub[256 * G2S];          // 20 KB (gemm f==0 path)
    int bid = blockIdx.x;
    int t = threadIdx.x;
    if (bid >= NB) {
        int gg = bid - NB;
        int r = (gg & 7) | ((gg >> 5) << 3);
        int h = (gg >> 3) & 3;
        if (r < nbx)
            gemm_core(Axb, Xraw, Asub, Bt, C, M, aS, aD, alphaS, alphaD,
                      flags[0], r, h);
        return;
    }
    // ---- CSR pass 2: one block per 256-node bucket, wave-privatized ----
    int b = bid;
    int w = t >> 6;
    part[t] = bcnt[t];
    sc4[0][t] = 0; sc4[1][t] = 0; sc4[2][t] = 0; sc4[3][t] = 0;
    __syncthreads();
#pragma unroll
    for (int off = 1; off < 256; off <<= 1) {   // inclusive scan of bucket sizes
        int v = (t >= off) ? part[t - off] : 0;
        __syncthreads();
        part[t] += v;
        __syncthreads();
    }
    int basepos = (b == 0) ? 0 : part[b - 1];
    int nEdges = min(bcnt[b], CAP);
    const unsigned int* bk = buckets + (size_t)b * CAP;
    for (int i = t; i < nEdges; i += 256)       // private histogram per wave
        atomicAdd(&sc4[w][bk[i] & 255], 1);
    __syncthreads();
    int c0 = sc4[0][t], c1 = sc4[1][t], c2 = sc4[2][t], c3 = sc4[3][t];
    int mycount = c0 + c1 + c2 + c3;
    sc[t] = mycount;
    __syncthreads();
#pragma unroll
    for (int off = 1; off < 256; off <<= 1) {   // inclusive scan of node counts
        int v = (t >= off) ? sc[t - off] : 0;
        __syncthreads();
        sc[t] += v;
        __syncthreads();
    }
    int excl = sc[t] - mycount;
    int gnode = b * 256 + t;
    if (gnode <= Nn) offs[gnode] = basepos + excl;
    // cursors = node base + exclusive wave base (same wave assignment below)
    sc4[0][t] = excl;
    sc4[1][t] = excl + c0;
    sc4[2][t] = excl + c0 + c1;
    sc4[3][t] = excl + c0 + c1 + c2;
    __syncthreads();
    for (int i = t; i < nEdges; i += 256) {
        unsigned int v = bk[i];
        int p = atomicAdd(&sc4[w][v & 255], 1);
        csr_src[basepos + p] = (int)(v >> 8);
    }
}

// ---- layer-2 gemm (H=1), LDS-staged A (hmidb row-major [M][256]) -----------
__global__ __launch_bounds__(256) void gemm2_kernel(const ushort* __restrict__ A,
                                                    const ushort* __restrict__ Bt,
                                                    ushort* __restrict__ C,
                                                    int M,
                                                    const void* __restrict__ aS,
                                                    const void* __restrict__ aD,
                                                    float* __restrict__ alphaS,
                                                    float* __restrict__ alphaD,
                                                    const int* __restrict__ flags) {
    __shared__ ushort Asub[256 * G2S];          // 20 KB
    const int KT = FIN >> 5;
    int t = threadIdx.x;
    int f = flags[0];
    int wave = t >> 6, lane = t & 63, quad = lane >> 4, l16 = lane & 15;
    int rbase = blockIdx.x * 256 + wave * 64;
    int lsub = (quad << 7) + (l16 << 3);
    int chunk = t & 3, rr = t >> 2;             // staging map: 4 thr/row
    floatx4 acc[4][4];
#pragma unroll
    for (int i = 0; i < 4; i++)
#pragma unroll
        for (int j = 0; j < 4; j++) acc[i][j] = (floatx4)0.f;

    for (int kb = 0; kb < FIN; kb += 32) {
        __syncthreads();                        // prior reads done
#pragma unroll
        for (int rd = 0; rd < 4; ++rd) {
            int row = blockIdx.x * 256 + rd * 64 + rr;
            if (row >= M) row = M - 1;
            uint4 v = *(const uint4*)(A + (size_t)row * FIN + kb + chunk * 8);
            *(uint4*)(Asub + (rd * 64 + rr) * G2S + chunk * 8) = v;
        }
        __syncthreads();
        int kt = kb >> 5;
        short8 b[4];
#pragma unroll
        for (int nt = 0; nt < 4; nt++) {
            b[nt] = *reinterpret_cast<const short8*>(
                Bt + (((size_t)(nt * KT + kt)) << 9) + lsub);
        }
#pragma unroll
        for (int mt = 0; mt < 4; mt++) {
            short8 a = *reinterpret_cast<const short8*>(
                Asub + (wave * 64 + mt * 16 + l16) * G2S + quad * 8);
#pragma unroll
            for (int nt = 0; nt < 4; nt++)
                acc[mt][nt] = __builtin_amdgcn_mfma_f32_16x16x32_bf16(
                    a, b[nt], acc[mt][nt], 0, 0, 0);
        }
    }
    float asv[4], adv[4];
#pragma unroll
    for (int nt = 0; nt < 4; nt++) {
        int col = nt * 16 + l16;
        asv[nt] = load_in(aS, col, f);
        adv[nt] = load_in(aD, col, f);
    }
#pragma unroll
    for (int mt = 0; mt < 4; mt++) {
#pragma unroll
        for (int r = 0; r < 4; r++) {
            int row = rbase + mt * 16 + quad * 4 + r;
            float ps = 0.f, pd = 0.f;
#pragma unroll
            for (int nt = 0; nt < 4; nt++) {
                float w = acc[mt][nt][r];
                ps += w * asv[nt];
                pd += w * adv[nt];
            }
#pragma unroll
            for (int off = 8; off > 0; off >>= 1) {
                ps += __shfl_xor(ps, off, 16);
                pd += __shfl_xor(pd, off, 16);
            }
            if (row < M) {
                if (l16 == 0) {
                    alphaS[row] = ps;
                    alphaD[row] = pd;
                }
#pragma unroll
                for (int nt = 0; nt < 4; nt++) {
                    int col = nt * 16 + l16;
                    C[(size_t)row * CH + col] = f2bf(acc[mt][nt][r]);
                }
            }
        }
    }
}

// ---- layer-1 aggregation, one plane (128 ch) per dispatch ------------------
// 1 wave/node, 8 edge slots (slot=lane>>3) x 8 ch-groups (cg=lane&7, 16ch).
// 16-edge granule (r9 structure); masked tail via p=0. Plain csr loads.
// Epilogue: ROW-MAJOR hmidb via NT stores (write-once; r16-measured win).
__global__ __launch_bounds__(256) void gat_node1_pass(
        const int* __restrict__ csr_src, const int* __restrict__ offs,
        const float* __restrict__ asrc, const float* __restrict__ adst,
        const ushort* __restrict__ h1p, const void* __restrict__ b1,
        ushort* __restrict__ hmidb, int Nn, const int* __restrict__ flags,
        int plane) {
    int f = flags[0];
    int wave = threadIdx.x >> 6, lane = threadIdx.x & 63;
    int n = blockIdx.x * 4 + wave;
    if (n >= Nn) return;
    int slot = lane >> 3, cg = lane & 7;       // 8 edge slots x 8 ch-groups
    int head = plane * 2 + (cg >> 2);
    float ad = adst[n * H1 + head];
    unsigned rowbase = (unsigned)(plane * Nn) * 128u + (unsigned)cg * 16u;
    int beg = offs[n], end = offs[n + 1];
    fx2 acc[8];
#pragma unroll
    for (int u = 0; u < 8; ++u) acc[u] = (fx2)0.f;
    float l = 0.f;

    int e = beg;
    while (e + 16 <= end) {                    // full granule, no masks
        int sa = csr_src[e + slot];
        int sb = csr_src[e + 8 + slot];
        float aa = asrc[sa * H1 + head];
        float ab = asrc[sb * H1 + head];
        const uint4* ra = (const uint4*)(h1p + rowbase + (unsigned)sa * 128u);
        const uint4* rb = (const uint4*)(h1p + rowbase + (unsigned)sb * 128u);
        uint4 va0 = ra[0], va1 = ra[1];
        uint4 vb0 = rb[0], vb1 = rb[1];
        float pa = edge_p(aa + ad);
        float pb = edge_p(ab + ad);
        accum16(acc, va0, va1, pa, l);
        accum16(acc, vb0, vb1, pb, l);
        e += 16;
    }
    if (e < end) {                             // masked tail (<16 edges)
        int ea = e + slot, eb = e + 8 + slot;
        bool oka = ea < end, okb = eb < end;
        int sa = csr_src[oka ? ea : beg];
        int sb = csr_src[okb ? eb : beg];
        float aa = asrc[sa * H1 + head];
        float ab = asrc[sb * H1 + head];
        const uint4* ra = (const uint4*)(h1p + rowbase + (unsigned)sa * 128u);
        const uint4* rb = (const uint4*)(h1p + rowbase + (unsigned)sb * 128u);
        uint4 va0 = ra[0], va1 = ra[1];
        uint4 vb0 = rb[0], vb1 = rb[1];
        float pa = edge_p(oka ? aa + ad : -1e30f);   // p = 0 when masked
        float pb = edge_p(okb ? ab + ad : -1e30f);
        accum16(acc, va0, va1, pa, l);
        accum16(acc, vb0, vb1, pb, l);
    }
    // reduce across the 8 edge slots (lane bits 3..5)
#pragma unroll
    for (int off = 8; off <= 32; off <<= 1) {
#pragma unroll
        for (int u = 0; u < 8; ++u) {
            acc[u][0] += __shfl_xor(acc[u][0], off);
            acc[u][1] += __shfl_xor(acc[u][1], off);
        }
        l += __shfl_xor(l, off);
    }
    if (slot == 0) {
        float inv = 1.f / (l + 1e-16f);
        int cb = plane * 128 + cg * 16;
        unsigned ow[8];
#pragma unroll
        for (int u = 0; u < 8; ++u) {
            float o0 = acc[u][0] * inv + load_in(b1, cb + 2 * u, f);
            float o1 = acc[u][1] * inv + load_in(b1, cb + 2 * u + 1, f);
            o0 = o0 > 0.f ? o0 : __expf(o0) - 1.f;   // ELU
            o1 = o1 > 0.f ? o1 : __expf(o1) - 1.f;
            ow[u] = (unsigned)f2bf(o0) | ((unsigned)f2bf(o1) << 16);
        }
        uintx4 st0 = {ow[0], ow[1], ow[2], ow[3]};
        uintx4 st1 = {ow[4], ow[5], ow[6], ow[7]};
        uintx4* dst = (uintx4*)(hmidb + (size_t)n * 256 + cb);
        __builtin_nontemporal_store(st0, dst);
        __builtin_nontemporal_store(st1, dst + 1);
    }
}

// ---- layer-2 aggregation: 1 wave/node, 8 edge slots x 8ch (uint4/lane) -----
__global__ __launch_bounds__(256) void gat_node2(const int* __restrict__ csr_src,
                                                 const int* __restrict__ offs,
                                                 const float* __restrict__ asrc,
                                                 const float* __restrict__ adst,
                                                 const ushort* __restrict__ h2b,
                                                 const void* __restrict__ b2,
                                                 void* __restrict__ out, int Nn,
                                                 const int* __restrict__ flags) {
    int f = flags[0];
    int wave = threadIdx.x >> 6, lane = threadIdx.x & 63;
    int n = blockIdx.x * 4 + wave;
    if (n >= Nn) return;
    int slot = lane >> 3, cg = lane & 7;
    float ad = adst[n];
    unsigned rowoff = (unsigned)cg * 8u;
    int beg = offs[n], end = offs[n + 1];
    fx2 acc[4];
#pragma unroll
    for (int u = 0; u < 4; ++u) acc[u] = (fx2)0.f;
    float l = 0.f;

    int e = beg;
    while (e + 16 <= end) {                    // full granule
        int sa = csr_src[e + slot];
        int sb = csr_src[e + 8 + slot];
        float aa = asrc[sa];
        float ab = asrc[sb];
        uint4 va = *(const uint4*)(h2b + rowoff + (unsigned)sa * 64u);
        uint4 vb = *(const uint4*)(h2b + rowoff + (unsigned)sb * 64u);
        float pa = edge_p(aa + ad);
        float pb = edge_p(ab + ad);
        accum8(acc, va, pa, l);
        accum8(acc, vb, pb, l);
        e += 16;
    }
    if (e < end) {                             // masked tail
        int ea = e + slot, eb = e + 8 + slot;
        bool oka = ea < end, okb = eb < end;
        int sa = csr_src[oka ? ea : beg];
        int sb = csr_src[okb ? eb : beg];
        float aa = asrc[sa];
        float ab = asrc[sb];
        uint4 va = *(const uint4*)(h2b + rowoff + (unsigned)sa * 64u);
        uint4 vb = *(const uint4*)(h2b + rowoff + (unsigned)sb * 64u);
        float pa = edge_p(oka ? aa + ad : -1e30f);
        float pb = edge_p(okb ? ab + ad : -1e30f);
        accum8(acc, va, pa, l);
        accum8(acc, vb, pb, l);
    }
#pragma unroll
    for (int off = 8; off <= 32; off <<= 1) {
#pragma unroll
        for (int u = 0; u < 4; ++u) {
            acc[u][0] += __shfl_xor(acc[u][0], off);
            acc[u][1] += __shfl_xor(acc[u][1], off);
        }
        l += __shfl_xor(l, off);
    }
    if (slot == 0) {
        float inv = 1.f / (l + 1e-16f);
        float o[8];
#pragma unroll
        for (int u = 0; u < 4; ++u) {
            o[2 * u]     = acc[u][0] * inv + load_in(b2, cg * 8 + 2 * u, f);
            o[2 * u + 1] = acc[u][1] * inv + load_in(b2, cg * 8 + 2 * u + 1, f);
        }
        if (f) {
            float* op = (float*)out + (unsigned)n * 64u + (unsigned)cg * 8u;
            floatx4 s0 = {o[0], o[1], o[2], o[3]};
            floatx4 s1 = {o[4], o[5], o[6], o[7]};
            __builtin_nontemporal_store(s0, (floatx4*)op);
            __builtin_nontemporal_store(s1, (floatx4*)(op + 4));
        } else {
            uintx4 st = {(unsigned)f2bf(o[0]) | ((unsigned)f2bf(o[1]) << 16),
                         (unsigned)f2bf(o[2]) | ((unsigned)f2bf(o[3]) << 16),
                         (unsigned)f2bf(o[4]) | ((unsigned)f2bf(o[5]) << 16),
                         (unsigned)f2bf(o[6]) | ((unsigned)f2bf(o[7]) << 16)};
            __builtin_nontemporal_store(st,
                (uintx4*)((ushort*)out + (unsigned)n * 64u + (unsigned)cg * 8u));
        }
    }
}

extern "C" void kernel_launch(void* const* d_in, const int* in_sizes, int n_in,
                              void* d_out, int out_size, void* d_ws, size_t ws_size,
                              hipStream_t stream) {
    const void* x   = d_in[0];
    const void* ei  = d_in[1];
    const void* W1  = d_in[2];
    const void* as1 = d_in[3];
    const void* ad1 = d_in[4];
    const void* b1  = d_in[5];
    const void* W2  = d_in[6];
    const void* as2 = d_in[7];
    const void* ad2 = d_in[8];
    const void* b2  = d_in[9];

    const int Nn = in_sizes[0] / FIN;      // 50000
    const int E  = in_sizes[1] / 2;        // 1600000
    const int ET = E + Nn;
    const int NB = (Nn + 255) >> 8;        // 196 buckets

    char* ws = (char*)d_ws;
    size_t off = 0;
    auto alloc = [&](size_t bytes) {
        size_t o = off;
        off += (bytes + 255) & ~(size_t)255;
        return o;
    };
    ushort* xb    = (ushort*)(ws + alloc((size_t)Nn * FIN * 2));   // packed tiles (f32 path)
    ushort* h1b   = (ushort*)(ws + alloc((size_t)Nn * FIN * 2));   // planar [2][Nn][128]
    ushort* hmidb = (ushort*)(ws + alloc((size_t)Nn * FIN * 2));   // row-major [Nn][256]
    ushort* h2b   = (ushort*)(ws + alloc((size_t)Nn * CH * 2));    // row-major [Nn][64]
    ushort* Wt1   = (ushort*)(ws + alloc((size_t)FIN * FIN * 2));  // packed tiles
    ushort* Wt2   = (ushort*)(ws + alloc((size_t)CH * FIN * 2));   // packed tiles
    float* as1f   = (float*)(ws + alloc((size_t)Nn * H1 * 4));
    float* ad1f   = (float*)(ws + alloc((size_t)Nn * H1 * 4));
    float* as2f   = (float*)(ws + alloc((size_t)Nn * 4));
    float* ad2f   = (float*)(ws + alloc((size_t)Nn * 4));
    int*   offs   = (int*)(ws + alloc((size_t)(Nn + 1) * 4));
    int*   csr    = (int*)(ws + alloc((size_t)ET * 4));
    unsigned int* buckets = (unsigned int*)(ws + alloc((size_t)256 * CAP * 4));
    int*   bcnt   = (int*)(ws + alloc(256 * 4));
    int*   flags  = (int*)(ws + alloc(256));
    (void)ws_size; (void)n_in; (void)out_size;

    probe_kernel<<<1, 256, 0, stream>>>((const uint4*)x, (const uint4*)ei, flags, bcnt);

    // fused prep (pack x if f32, W1^T, W2^T) | bucket pass 1
    int PB_conv = (Nn * FIN) / 2048;                       // one 16B chunk/thread
    int PB_tr   = (FIN * FIN + CH * FIN) / 2048;           // 40
    int PB_bkt  = (ET + 4095) / 4096;
    prep_bucket_kernel<<<PB_conv + PB_tr + PB_bkt, 256, 0, stream>>>(
        x, W1, W2, xb, Wt1, Wt2, ei, bcnt, buckets,
        E, ET, Nn, flags, PB_conv, PB_conv + PB_tr);

    // fused: CSR pass 2 (first) + XCD-grouped gemm1 (+alpha, planar-128 C)
    int nbx = (Nn + 255) / 256;            // 196 row-blocks
    int ngrp = (nbx + 7) >> 3;             // 25 row-groups of 8
    gemm1_pass2_kernel<<<NB + ngrp * 32, 256, 0, stream>>>(
        xb, (const ushort*)x, Wt1, h1b, Nn, as1, ad1, as1f, ad1f,
        flags, NB, nbx, bcnt, buckets, offs, csr, Nn);

    // layer-1 aggregation: one dispatch per 128-ch plane (time-separated)
    gat_node1_pass<<<(Nn + 3) / 4, 256, 0, stream>>>(
        csr, offs, as1f, ad1f, h1b, b1, hmidb, Nn, flags, 0);
    gat_node1_pass<<<(Nn + 3) / 4, 256, 0, stream>>>(
        csr, offs, as1f, ad1f, h1b, b1, hmidb, Nn, flags, 1);

    // layer 2
    gemm2_kernel<<<(Nn + 255) / 256, 256, 0, stream>>>(
        hmidb, Wt2, h2b, Nn, as2, ad2, as2f, ad2f, flags);
    gat_node2<<<(Nn + 3) / 4, 256, 0, stream>>>(csr, offs, as2f, ad2f, h2b, b2, d_out, Nn, flags);
}